// Round 1
// baseline (1821.829 us; speedup 1.0000x reference)
//
#include <hip/hip_runtime.h>
#include <cstdint>
#include <cstddef>

// ---- problem constants (fixed by setup_inputs) ----
constexpr int B_   = 2;
constexpr int N_   = 2000;          // proposals per image
constexpr int M_   = 64;            // gt boxes per image
constexpr int NB_  = N_ + M_;       // 2064 candidates per image
constexpr int C_   = 256;
constexpr int H_   = 64;
constexpr int W_   = 64;
constexpr int RPI  = 512;           // BATCH_PER_IMG
constexpr int RTOT = B_ * RPI;      // 1024 rois
constexpr int FG_CAP_ = 128;
constexpr int D_   = C_ * 49;       // 12544
constexpr int FC_  = 1024;
constexpr int NBOX = 320;           // NUM_CLASSES*4
constexpr int OUTC = 401;           // 81 + 320
constexpr float IOU_T   = 0.5f;
constexpr float STRIDE_ = 16.0f;

// ---------------------------------------------------------------------------
// K0: transpose features (B,C,H,W) -> (B,H*W,C) for coalesced channel reads
// ---------------------------------------------------------------------------
__global__ __launch_bounds__(256) void k_transpose(const float* __restrict__ in,
                                                   float* __restrict__ out) {
  __shared__ float tile[32][33];
  int b   = blockIdx.z;
  int hw0 = blockIdx.x * 32;
  int c0  = blockIdx.y * 32;
  int tx  = threadIdx.x, ty = threadIdx.y;  // (32,8)
#pragma unroll
  for (int i = ty; i < 32; i += 8)
    tile[i][tx] = in[((size_t)b * C_ + c0 + i) * (H_ * W_) + hw0 + tx];
  __syncthreads();
#pragma unroll
  for (int i = ty; i < 32; i += 8)
    out[((size_t)b * (H_ * W_) + hw0 + i) * C_ + c0 + tx] = tile[tx][i];
}

// ---------------------------------------------------------------------------
// K1: IoU matching + fg/bg sampling (exact JAX semantics), one block per image
// ---------------------------------------------------------------------------
__global__ __launch_bounds__(1024) void k_select(const float* __restrict__ prop,
                                                 const float* __restrict__ gt,
                                                 const float* __restrict__ rnd,
                                                 float* __restrict__ rois) {
  __shared__ float s_gt[M_ * 4];
  __shared__ float s_area_g[M_];
  __shared__ float s_rand[NB_];
  __shared__ unsigned char s_fg[NB_];
  __shared__ unsigned char s_sel[NB_];  // 0 none, 1 bg-sel, 2 fg-sel
  __shared__ int s_fgcnt;

  int b = blockIdx.x;
  int t = threadIdx.x;
  if (t == 0) s_fgcnt = 0;
  if (t < M_ * 4) s_gt[t] = gt[(size_t)b * M_ * 4 + t];
  __syncthreads();
  if (t < M_) {
    float x1 = s_gt[t * 4], y1 = s_gt[t * 4 + 1];
    float x2 = s_gt[t * 4 + 2], y2 = s_gt[t * 4 + 3];
    s_area_g[t] = (x2 - x1) * (y2 - y1);
  }
  __syncthreads();

  int localfg = 0;
  for (int j = t; j < NB_; j += 1024) {
    float bx1, by1, bx2, by2;
    if (j < N_) {
      const float* p = prop + ((size_t)b * N_ + j) * 4;
      bx1 = p[0]; by1 = p[1]; bx2 = p[2]; by2 = p[3];
    } else {
      const float* p = s_gt + (j - N_) * 4;
      bx1 = p[0]; by1 = p[1]; bx2 = p[2]; by2 = p[3];
    }
    float area_p = (bx2 - bx1) * (by2 - by1);
    float best = 0.f;
    for (int g = 0; g < M_; ++g) {
      float gx1 = s_gt[g * 4], gy1 = s_gt[g * 4 + 1];
      float gx2 = s_gt[g * 4 + 2], gy2 = s_gt[g * 4 + 3];
      float lx = fmaxf(gx1, bx1), lyv = fmaxf(gy1, by1);
      float rx = fminf(gx2, bx2), ry = fminf(gy2, by2);
      float w = fmaxf(rx - lx, 0.f), h = fmaxf(ry - lyv, 0.f);
      float inter = w * h;
      float uni = s_area_g[g] + area_p - inter;
      float iou = inter > 0.f ? inter / uni : 0.f;
      best = fmaxf(best, iou);
    }
    int fg = (best >= IOU_T) ? 1 : 0;
    s_fg[j]   = (unsigned char)fg;
    s_rand[j] = rnd[(size_t)b * NB_ + j];
    localfg += fg;
  }
  atomicAdd(&s_fgcnt, localfg);
  __syncthreads();

  int fgcnt  = s_fgcnt;
  int num_fg = min(fgcnt, FG_CAP_);
  int bgcnt  = NB_ - fgcnt;
  int num_bg = min(RPI - num_fg, bgcnt);

  // rank among same class (stable: ties broken by lower index first)
  for (int j = t; j < NB_; j += 1024) {
    int fg   = (int)s_fg[j];
    float rj = s_rand[j];
    int rank = 0;
    for (int k = 0; k < NB_; ++k) {
      if ((int)s_fg[k] != fg) continue;
      float rk = s_rand[k];
      rank += (rk < rj || (rk == rj && k < j)) ? 1 : 0;
    }
    int lim = fg ? num_fg : num_bg;
    s_sel[j] = (rank < lim) ? (unsigned char)(fg ? 2 : 1) : (unsigned char)0;
  }
  __syncthreads();

  int S = num_fg + num_bg;  // total selected (<= 512)
  // output position per lax.top_k: fg (score 2) ascending idx, then bg
  // (score 1) ascending, then score-0 filler ascending.
  for (int j = t; j < NB_; j += 1024) {
    int sl  = (int)s_sel[j];
    int pos = -1;
    if (sl == 2) {
      int cnt = 0;
      for (int k = 0; k < j; ++k) cnt += (s_sel[k] == 2);
      pos = cnt;
    } else if (sl == 1) {
      int cnt = 0;
      for (int k = 0; k < j; ++k) cnt += (s_sel[k] == 1);
      pos = num_fg + cnt;
    } else if (S < RPI) {
      int cnt = 0;
      for (int k = 0; k < j; ++k) cnt += (s_sel[k] == 0);
      if (cnt < RPI - S) pos = S + cnt;
    }
    if (pos >= 0) {
      float bx[4];
      if (j < N_) {
        const float* p = prop + ((size_t)b * N_ + j) * 4;
        bx[0] = p[0]; bx[1] = p[1]; bx[2] = p[2]; bx[3] = p[3];
      } else {
        const float* p = s_gt + (j - N_) * 4;
        bx[0] = p[0]; bx[1] = p[1]; bx[2] = p[2]; bx[3] = p[3];
      }
      float* o = rois + ((size_t)b * RPI + pos) * 4;
      o[0] = bx[0]; o[1] = bx[1]; o[2] = bx[2]; o[3] = bx[3];
    }
  }
}

// ---------------------------------------------------------------------------
// K2: ROI align. block = 256 channels, grid = (49 bins, 1024 rois).
// pooled layout: (r, bin, c) -> coalesced writes; k-permutation folded
// into GEMM1's B-row map (d = c*49 + bin).
// ---------------------------------------------------------------------------
__global__ __launch_bounds__(256) void k_roialign(const float* __restrict__ fT,
                                                  const float* __restrict__ rois,
                                                  float* __restrict__ pooled) {
  int bin = blockIdx.x;  // 0..48
  int r   = blockIdx.y;  // 0..1023
  int c   = threadIdx.x;
  int by = bin / 7, bx = bin % 7;
  int img = r >> 9;  // r / 512
  const float* rp = rois + (size_t)r * 4;
  float x1 = rp[0] / STRIDE_ - 0.5f;
  float y1 = rp[1] / STRIDE_ - 0.5f;
  float x2 = rp[2] / STRIDE_ - 0.5f;
  float y2 = rp[3] / STRIDE_ - 0.5f;
  float stx = (x2 - x1) / 7.0f;
  float sty = (y2 - y1) / 7.0f;
  const float* fb = fT + (size_t)img * H_ * W_ * C_;
  float acc = 0.f;
#pragma unroll
  for (int s = 0; s < 4; ++s) {
    int oy = s >> 1, ox = s & 1;
    float gx = ((float)(2 * bx + ox) + 0.5f) * 0.5f;
    float gy = ((float)(2 * by + oy) + 0.5f) * 0.5f;
    float xs = x1 + gx * stx;
    float ys = y1 + gy * sty;
    xs = fminf(fmaxf(xs, 0.f), (float)(W_ - 1));
    ys = fminf(fmaxf(ys, 0.f), (float)(H_ - 1));
    int x0 = (int)floorf(xs);
    int y0 = (int)floorf(ys);
    int x1i = min(x0 + 1, W_ - 1);
    int y1i = min(y0 + 1, H_ - 1);
    float lx = xs - (float)x0;
    float ly = ys - (float)y0;
    float v00 = fb[((size_t)y0 * W_ + x0) * C_ + c];
    float v01 = fb[((size_t)y0 * W_ + x1i) * C_ + c];
    float v10 = fb[((size_t)y1i * W_ + x0) * C_ + c];
    float v11 = fb[((size_t)y1i * W_ + x1i) * C_ + c];
    float wy1 = ly, wy0 = 1.f - ly, wx1 = lx, wx0 = 1.f - lx;
    acc += v00 * wy0 * wx0 + v01 * wy0 * wx1 + v10 * wy1 * wx0 + v11 * wy1 * wx1;
  }
  pooled[((size_t)r * 49 + bin) * C_ + c] = acc * 0.25f;
}

// ---------------------------------------------------------------------------
// K3: fp32 tiled GEMM, 64x64 tile, BK=16, 256 threads, 4x4 microtile.
// rowmap: B row index = (k%256)*49 + (k/256)  (pooled k' = bin*256+c -> fc1_w
// row c*49+bin). vecB=0 -> guarded scalar B loads (for N=81 head).
// ---------------------------------------------------------------------------
__global__ __launch_bounds__(256) void k_gemm64(
    const float* __restrict__ A, const float* __restrict__ Bm,
    const float* __restrict__ bias, float* __restrict__ Cm,
    int M, int N, int K, int lda, int ldb, int ldc, int colOff,
    int rowmap, int relu, int vecB) {
  __shared__ float As[16][68];
  __shared__ float Bs[16][68];
  int t  = threadIdx.x;
  int m0 = blockIdx.x * 64, n0 = blockIdx.y * 64;
  int ar = t >> 2, ak = (t & 3) * 4;   // A: 64 rows x 16 k
  int bk = t >> 4, bn = (t & 15) * 4;  // B: 16 k x 64 n
  int ty = t >> 4, tx = t & 15;
  float acc[4][4] = {};
  for (int k0 = 0; k0 < K; k0 += 16) {
    float4 a4 = *(const float4*)(A + (size_t)(m0 + ar) * lda + (k0 + ak));
    As[ak + 0][ar] = a4.x; As[ak + 1][ar] = a4.y;
    As[ak + 2][ar] = a4.z; As[ak + 3][ar] = a4.w;
    int krow = k0 + bk;
    int brow = rowmap ? ((krow & 255) * 49 + (krow >> 8)) : krow;
    if (vecB) {
      float4 b4 = *(const float4*)(Bm + (size_t)brow * ldb + n0 + bn);
      Bs[bk][bn + 0] = b4.x; Bs[bk][bn + 1] = b4.y;
      Bs[bk][bn + 2] = b4.z; Bs[bk][bn + 3] = b4.w;
    } else {
#pragma unroll
      for (int q = 0; q < 4; ++q) {
        int n = n0 + bn + q;
        Bs[bk][bn + q] = (n < N) ? Bm[(size_t)brow * ldb + n] : 0.f;
      }
    }
    __syncthreads();
#pragma unroll
    for (int kk = 0; kk < 16; ++kk) {
      float4 av = *(const float4*)&As[kk][ty * 4];
      float4 bv = *(const float4*)&Bs[kk][tx * 4];
      float a[4] = {av.x, av.y, av.z, av.w};
      float bb[4] = {bv.x, bv.y, bv.z, bv.w};
#pragma unroll
      for (int i = 0; i < 4; ++i)
#pragma unroll
        for (int j = 0; j < 4; ++j)
          acc[i][j] = fmaf(a[i], bb[j], acc[i][j]);
    }
    __syncthreads();
  }
#pragma unroll
  for (int i = 0; i < 4; ++i) {
    int m = m0 + ty * 4 + i;
#pragma unroll
    for (int j = 0; j < 4; ++j) {
      int n = n0 + tx * 4 + j;
      if (n < N) {
        float v = acc[i][j] + bias[n];
        if (relu) v = fmaxf(v, 0.f);
        Cm[(size_t)m * ldc + colOff + n] = v;
      }
    }
  }
}

// ---------------------------------------------------------------------------
extern "C" void kernel_launch(void* const* d_in, const int* in_sizes, int n_in,
                              void* d_out, int out_size, void* d_ws, size_t ws_size,
                              hipStream_t stream) {
  const float* features = (const float*)d_in[0];
  const float* prop     = (const float*)d_in[1];
  const float* gt       = (const float*)d_in[2];
  // d_in[3] = gt_classes (unused: cls output is discarded by reference)
  const float* rnd      = (const float*)d_in[4];
  const float* fc1_w    = (const float*)d_in[5];
  const float* fc1_b    = (const float*)d_in[6];
  const float* fc2_w    = (const float*)d_in[7];
  const float* fc2_b    = (const float*)d_in[8];
  const float* cls_w    = (const float*)d_in[9];
  const float* cls_b    = (const float*)d_in[10];
  const float* box_w    = (const float*)d_in[11];
  const float* box_b    = (const float*)d_in[12];
  float* out = (float*)d_out;

  float* ws     = (float*)d_ws;
  float* fT     = ws;                                  // 2,097,152 f
  float* rois   = fT + (size_t)B_ * H_ * W_ * C_;      // 4,096 f
  float* pooled = rois + (size_t)RTOT * 4;             // 12,845,056 f
  float* x1     = pooled + (size_t)RTOT * 49 * C_;     // 1,048,576 f
  float* x2     = x1 + (size_t)RTOT * FC_;             // 1,048,576 f

  k_transpose<<<dim3(128, 8, B_), dim3(32, 8), 0, stream>>>(features, fT);
  k_select<<<dim3(B_), dim3(1024), 0, stream>>>(prop, gt, rnd, rois);
  k_roialign<<<dim3(49, RTOT), dim3(256), 0, stream>>>(fT, rois, pooled);
  // FC1: x1 = relu(pooled @ fc1_w' + fc1_b), rowmap folds the (c,bin) permute
  k_gemm64<<<dim3(16, 16), dim3(256), 0, stream>>>(
      pooled, fc1_w, fc1_b, x1, RTOT, FC_, D_, D_, FC_, FC_, 0, 1, 1, 1);
  // FC2: x2 = relu(x1 @ fc2_w + fc2_b)
  k_gemm64<<<dim3(16, 16), dim3(256), 0, stream>>>(
      x1, fc2_w, fc2_b, x2, RTOT, FC_, FC_, FC_, FC_, FC_, 0, 0, 1, 1);
  // heads: out[:, :81] = x2 @ cls_w + cls_b ; out[:, 81:] = x2 @ box_w + box_b
  k_gemm64<<<dim3(16, 2), dim3(256), 0, stream>>>(
      x2, cls_w, cls_b, out, RTOT, 81, FC_, FC_, 81, OUTC, 0, 0, 0, 0);
  k_gemm64<<<dim3(16, 5), dim3(256), 0, stream>>>(
      x2, box_w, box_b, out, RTOT, NBOX, FC_, FC_, NBOX, OUTC, 81, 0, 0, 1);
}

// Round 2
// 865.232 us; speedup vs baseline: 2.1056x; 2.1056x over previous
//
#include <hip/hip_runtime.h>
#include <cstdint>
#include <cstddef>

// ---- problem constants ----
constexpr int B_   = 2;
constexpr int N_   = 2000;
constexpr int M_   = 64;
constexpr int NB_  = N_ + M_;       // 2064
constexpr int C_   = 256;
constexpr int H_   = 64;
constexpr int W_   = 64;
constexpr int RPI  = 512;
constexpr int RTOT = B_ * RPI;      // 1024
constexpr int FG_CAP_ = 128;
constexpr int D_   = C_ * 49;       // 12544
constexpr int FC_  = 1024;
constexpr int OUTC = 401;           // 81 + 320
constexpr int KT1  = D_ / 32;       // 392 k-tiles for FC1
constexpr int KT2  = FC_ / 32;      // 32 k-tiles for FC2/heads
constexpr float IOU_T = 0.5f;

typedef _Float16 f16;
typedef f16   f16x8 __attribute__((ext_vector_type(8)));
typedef float f32x4 __attribute__((ext_vector_type(4)));

// fragment-linear tile: 16 rows x 32 k, stored as 64 lanes x 8 f16 (16B/lane).
// lane = (k_in_tile>>3)*16 + (row&15), elem j = k&7.  (A-layout m120-verified;
// B uses same shape with row->col.)  One tile = 1 KB = one global_load_lds x16.

__device__ __forceinline__ void tile_load16(const void* g, void* l) {
  __builtin_amdgcn_global_load_lds(
      (const __attribute__((address_space(1))) unsigned int*)g,
      (__attribute__((address_space(3))) unsigned int*)l, 16, 0, 0);
}

// ---------------------------------------------------------------------------
// K0: features (B,C,H,W) -> (B,H*W,C)
// ---------------------------------------------------------------------------
__global__ __launch_bounds__(256) void k_transpose(const float* __restrict__ in,
                                                   float* __restrict__ out) {
  __shared__ float tile[32][33];
  int b = blockIdx.z, hw0 = blockIdx.x * 32, c0 = blockIdx.y * 32;
  int tx = threadIdx.x, ty = threadIdx.y;
#pragma unroll
  for (int i = ty; i < 32; i += 8)
    tile[i][tx] = in[((size_t)b * C_ + c0 + i) * (H_ * W_) + hw0 + tx];
  __syncthreads();
#pragma unroll
  for (int i = ty; i < 32; i += 8)
    out[((size_t)b * (H_ * W_) + hw0 + i) * C_ + c0 + tx] = tile[tx][i];
}

// ---------------------------------------------------------------------------
// K1: IoU match + sample (exact JAX stable-rank semantics) — passed round 1
// ---------------------------------------------------------------------------
__global__ __launch_bounds__(1024) void k_select(const float* __restrict__ prop,
                                                 const float* __restrict__ gt,
                                                 const float* __restrict__ rnd,
                                                 float* __restrict__ rois) {
  __shared__ float s_gt[M_ * 4];
  __shared__ float s_area_g[M_];
  __shared__ float s_rand[NB_];
  __shared__ unsigned char s_fg[NB_];
  __shared__ unsigned char s_sel[NB_];
  __shared__ int s_fgcnt;
  int b = blockIdx.x, t = threadIdx.x;
  if (t == 0) s_fgcnt = 0;
  if (t < M_ * 4) s_gt[t] = gt[(size_t)b * M_ * 4 + t];
  __syncthreads();
  if (t < M_) {
    float x1 = s_gt[t*4], y1 = s_gt[t*4+1], x2 = s_gt[t*4+2], y2 = s_gt[t*4+3];
    s_area_g[t] = (x2 - x1) * (y2 - y1);
  }
  __syncthreads();
  int localfg = 0;
  for (int j = t; j < NB_; j += 1024) {
    float bx1, by1, bx2, by2;
    if (j < N_) {
      const float* p = prop + ((size_t)b * N_ + j) * 4;
      bx1 = p[0]; by1 = p[1]; bx2 = p[2]; by2 = p[3];
    } else {
      const float* p = s_gt + (j - N_) * 4;
      bx1 = p[0]; by1 = p[1]; bx2 = p[2]; by2 = p[3];
    }
    float area_p = (bx2 - bx1) * (by2 - by1);
    float best = 0.f;
    for (int g = 0; g < M_; ++g) {
      float lx = fmaxf(s_gt[g*4], bx1),   lyv = fmaxf(s_gt[g*4+1], by1);
      float rx = fminf(s_gt[g*4+2], bx2), ry  = fminf(s_gt[g*4+3], by2);
      float w = fmaxf(rx - lx, 0.f), h = fmaxf(ry - lyv, 0.f);
      float inter = w * h;
      float iou = inter > 0.f ? inter / (s_area_g[g] + area_p - inter) : 0.f;
      best = fmaxf(best, iou);
    }
    int fg = (best >= IOU_T) ? 1 : 0;
    s_fg[j] = (unsigned char)fg;
    s_rand[j] = rnd[(size_t)b * NB_ + j];
    localfg += fg;
  }
  atomicAdd(&s_fgcnt, localfg);
  __syncthreads();
  int fgcnt  = s_fgcnt;
  int num_fg = min(fgcnt, FG_CAP_);
  int num_bg = min(RPI - num_fg, NB_ - fgcnt);
  for (int j = t; j < NB_; j += 1024) {
    int fg = (int)s_fg[j];
    float rj = s_rand[j];
    int rank = 0;
    for (int k = 0; k < NB_; ++k) {
      if ((int)s_fg[k] != fg) continue;
      float rk = s_rand[k];
      rank += (rk < rj || (rk == rj && k < j)) ? 1 : 0;
    }
    int lim = fg ? num_fg : num_bg;
    s_sel[j] = (rank < lim) ? (unsigned char)(fg ? 2 : 1) : (unsigned char)0;
  }
  __syncthreads();
  int S = num_fg + num_bg;
  for (int j = t; j < NB_; j += 1024) {
    int sl = (int)s_sel[j];
    int pos = -1;
    if (sl == 2) {
      int cnt = 0;
      for (int k = 0; k < j; ++k) cnt += (s_sel[k] == 2);
      pos = cnt;
    } else if (sl == 1) {
      int cnt = 0;
      for (int k = 0; k < j; ++k) cnt += (s_sel[k] == 1);
      pos = num_fg + cnt;
    } else if (S < RPI) {
      int cnt = 0;
      for (int k = 0; k < j; ++k) cnt += (s_sel[k] == 0);
      if (cnt < RPI - S) pos = S + cnt;
    }
    if (pos >= 0) {
      float bx[4];
      if (j < N_) {
        const float* p = prop + ((size_t)b * N_ + j) * 4;
        bx[0]=p[0]; bx[1]=p[1]; bx[2]=p[2]; bx[3]=p[3];
      } else {
        const float* p = s_gt + (j - N_) * 4;
        bx[0]=p[0]; bx[1]=p[1]; bx[2]=p[2]; bx[3]=p[3];
      }
      float* o = rois + ((size_t)b * RPI + pos) * 4;
      o[0]=bx[0]; o[1]=bx[1]; o[2]=bx[2]; o[3]=bx[3];
    }
  }
}

// ---------------------------------------------------------------------------
// K2: ROI align -> A1 hi/lo fp16 fragment-linear directly.
// block = (bin, mt): 16 rois x 256 ch, LDS-staged, coalesced frag writes.
// ---------------------------------------------------------------------------
__global__ __launch_bounds__(256) void k_roialign(const float* __restrict__ fT,
                                                  const float* __restrict__ rois,
                                                  f16* __restrict__ Ahi,
                                                  f16* __restrict__ Alo) {
  __shared__ float sv[8][257];
  int bin = blockIdx.x, mt = blockIdx.y;
  int c = threadIdx.x;
  int by = bin / 7, bx = bin % 7;
  for (int pass = 0; pass < 2; ++pass) {
    for (int r8 = 0; r8 < 8; ++r8) {
      int r = mt * 16 + pass * 8 + r8;
      const float* rp = rois + (size_t)r * 4;
      float x1 = rp[0] * 0.0625f - 0.5f;
      float y1 = rp[1] * 0.0625f - 0.5f;
      float x2 = rp[2] * 0.0625f - 0.5f;
      float y2 = rp[3] * 0.0625f - 0.5f;
      float stx = (x2 - x1) * (1.0f / 7.0f);
      float sty = (y2 - y1) * (1.0f / 7.0f);
      const float* fb = fT + (size_t)(r >> 9) * H_ * W_ * C_;
      float acc = 0.f;
#pragma unroll
      for (int s = 0; s < 4; ++s) {
        int oy = s >> 1, ox = s & 1;
        float xs = x1 + ((float)(2 * bx + ox) + 0.5f) * 0.5f * stx;
        float ys = y1 + ((float)(2 * by + oy) + 0.5f) * 0.5f * sty;
        xs = fminf(fmaxf(xs, 0.f), (float)(W_ - 1));
        ys = fminf(fmaxf(ys, 0.f), (float)(H_ - 1));
        int x0 = (int)floorf(xs), y0 = (int)floorf(ys);
        int x1i = min(x0 + 1, W_ - 1), y1i = min(y0 + 1, H_ - 1);
        float lx = xs - (float)x0, ly = ys - (float)y0;
        float v00 = fb[((size_t)y0 * W_ + x0) * C_ + c];
        float v01 = fb[((size_t)y0 * W_ + x1i) * C_ + c];
        float v10 = fb[((size_t)y1i * W_ + x0) * C_ + c];
        float v11 = fb[((size_t)y1i * W_ + x1i) * C_ + c];
        acc += v00*(1.f-ly)*(1.f-lx) + v01*(1.f-ly)*lx + v10*ly*(1.f-lx) + v11*ly*lx;
      }
      sv[r8][c] = acc * 0.25f;
    }
    __syncthreads();
    // writeout: thread -> one 16B chunk (8 f16) per buffer
    int kt   = c >> 5;
    int l5   = c & 31;
    int quad = l5 >> 3;
    int r8   = l5 & 7;
    int lane = quad * 16 + pass * 8 + r8;
    int cbase = kt * 32 + quad * 8;
    f16x8 hv, lv;
#pragma unroll
    for (int jj = 0; jj < 8; ++jj) {
      float v = sv[r8][cbase + jj];
      f16 h = (f16)v;
      hv[jj] = h;
      lv[jj] = (f16)(v - (float)h);
    }
    size_t off = ((size_t)(mt * KT1 + bin * 8 + kt) * 64 + lane) * 8;
    *(f16x8*)(Ahi + off) = hv;
    *(f16x8*)(Alo + off) = lv;
    __syncthreads();
  }
}

// ---------------------------------------------------------------------------
// K3: weight -> fp16 fragment-linear. mode 0: direct (ldb=1024);
// mode 1: fc1 row-permute d=(k&255)*49+(k>>8); mode 2: concat cls|box pad-512.
// ---------------------------------------------------------------------------
__global__ __launch_bounds__(256) void k_convw(const float* __restrict__ src,
                                               const float* __restrict__ src2,
                                               f16* __restrict__ dst,
                                               int KTtot, int mode) {
  int q = blockIdx.x * 256 + threadIdx.x;
  int lane = q & 63, tile = q >> 6;
  int nt = tile / KTtot, kt = tile - nt * KTtot;
  int n  = nt * 16 + (lane & 15);
  int k0 = kt * 32 + (lane >> 4) * 8;
  f16x8 h;
#pragma unroll
  for (int jj = 0; jj < 8; ++jj) {
    int k = k0 + jj;
    float v;
    if (mode == 0) {
      v = src[(size_t)k * 1024 + n];
    } else if (mode == 1) {
      int row = (k & 255) * 49 + (k >> 8);
      v = src[(size_t)row * 1024 + n];
    } else {
      v = (n < 81) ? src[(size_t)k * 81 + n]
                   : ((n < 401) ? src2[(size_t)k * 320 + (n - 81)] : 0.f);
    }
    h[jj] = (f16)v;
  }
  *(f16x8*)(dst + (size_t)q * 8) = h;
}

// ---------------------------------------------------------------------------
// K4: MFMA GEMM. BM=BN=128, BK=32, 4 waves (2x2) each 64x64.
// A = hi/lo fp16 frag-linear (2 mfma), B = fp16 frag-linear, split-K over z.
// ---------------------------------------------------------------------------
__global__ __launch_bounds__(256, 2) void k_gemm_mfma(
    const f16* __restrict__ Ahi, const f16* __restrict__ Alo,
    const f16* __restrict__ Bw, float* __restrict__ P,
    int N, int KTtot, int ktPerSplit) {
  __shared__ f16 sAh[8 * 512];
  __shared__ f16 sAl[8 * 512];
  __shared__ f16 sB[8 * 512];
  int tid = threadIdx.x;
  int lane = tid & 63, w = tid >> 6;
  int wm = w >> 1, wn = w & 1;
  int bm = blockIdx.x, bn = blockIdx.y, z = blockIdx.z;
  int kt0 = z * ktPerSplit, ktEnd = kt0 + ktPerSplit;

  f32x4 acc[4][4];
#pragma unroll
  for (int i = 0; i < 4; ++i)
#pragma unroll
    for (int j = 0; j < 4; ++j) {
      f32x4 zv = {0.f, 0.f, 0.f, 0.f};
      acc[i][j] = zv;
    }

  for (int kt = kt0; kt < ktEnd; ++kt) {
    // stage 24 tiles (1 KB each): wave w handles 6
#pragma unroll
    for (int tt = 0; tt < 6; ++tt) {
      int t = 6 * w + tt;
      const f16* g;
      f16* l;
      if (t < 8)       { g = Ahi + ((size_t)(bm*8 + t)      * KTtot + kt) * 512; l = sAh + t * 512; }
      else if (t < 16) { g = Alo + ((size_t)(bm*8 + (t-8))  * KTtot + kt) * 512; l = sAl + (t-8) * 512; }
      else             { g = Bw  + ((size_t)(bn*8 + (t-16)) * KTtot + kt) * 512; l = sB  + (t-16) * 512; }
      tile_load16(g + lane * 8, l);
    }
    __syncthreads();  // drains vmcnt -> LDS valid
    f16x8 ah[4], al[4], bw[4];
#pragma unroll
    for (int i = 0; i < 4; ++i) {
      ah[i] = *(const f16x8*)(sAh + (wm*4 + i) * 512 + lane * 8);
      al[i] = *(const f16x8*)(sAl + (wm*4 + i) * 512 + lane * 8);
      bw[i] = *(const f16x8*)(sB  + (wn*4 + i) * 512 + lane * 8);
    }
#pragma unroll
    for (int i = 0; i < 4; ++i)
#pragma unroll
      for (int j = 0; j < 4; ++j) {
        acc[i][j] = __builtin_amdgcn_mfma_f32_16x16x32_f16(ah[i], bw[j], acc[i][j], 0, 0, 0);
        acc[i][j] = __builtin_amdgcn_mfma_f32_16x16x32_f16(al[i], bw[j], acc[i][j], 0, 0, 0);
      }
    __syncthreads();
  }

  // epilogue: C/D layout col=lane&15, row=quad*4+reg (m89/m91 verified)
  int quad = lane >> 4, cl = lane & 15;
  float* Pz = P + (size_t)z * 1024 * (size_t)N;
#pragma unroll
  for (int i = 0; i < 4; ++i) {
    int row = bm * 128 + wm * 64 + i * 16 + quad * 4;
#pragma unroll
    for (int j = 0; j < 4; ++j) {
      int col = bn * 128 + wn * 64 + j * 16 + cl;
#pragma unroll
      for (int r = 0; r < 4; ++r)
        Pz[(size_t)(row + r) * N + col] = acc[i][j][r];
    }
  }
}

// ---------------------------------------------------------------------------
// K5: split-K reduce + bias + relu -> next layer's A hi/lo frag-linear (KT=32)
// ---------------------------------------------------------------------------
__global__ __launch_bounds__(256) void k_combine(const float* __restrict__ P,
                                                 const float* __restrict__ bias,
                                                 f16* __restrict__ Ahi,
                                                 f16* __restrict__ Alo,
                                                 int nsplit) {
  int q = blockIdx.x * 256 + threadIdx.x;  // 131072 chunks
  int lane = q & 63, tile = q >> 6;
  int mt = tile >> 5, kt = tile & 31;
  int m  = mt * 16 + (lane & 15);
  int n0 = kt * 32 + (lane >> 4) * 8;
  float v[8];
#pragma unroll
  for (int jj = 0; jj < 8; ++jj) v[jj] = bias[n0 + jj];
  for (int s = 0; s < nsplit; ++s) {
    const float* p = P + (size_t)s * 1048576 + (size_t)m * 1024 + n0;
#pragma unroll
    for (int jj = 0; jj < 8; ++jj) v[jj] += p[jj];
  }
  f16x8 hv, lv;
#pragma unroll
  for (int jj = 0; jj < 8; ++jj) {
    float x = fmaxf(v[jj], 0.f);
    f16 h = (f16)x;
    hv[jj] = h;
    lv[jj] = (f16)(x - (float)h);
  }
  *(f16x8*)(Ahi + (size_t)q * 8) = hv;
  *(f16x8*)(Alo + (size_t)q * 8) = lv;
}

// ---------------------------------------------------------------------------
// K6: heads split-K reduce + concat bias -> out (1024 x 401 fp32)
// ---------------------------------------------------------------------------
__global__ __launch_bounds__(256) void k_out(const float* __restrict__ P,
                                             const float* __restrict__ cls_b,
                                             const float* __restrict__ box_b,
                                             float* __restrict__ out, int nsplit) {
  int idx = blockIdx.x * 256 + threadIdx.x;
  if (idx >= RTOT * OUTC) return;
  int m = idx / OUTC, n = idx - m * OUTC;
  float v = (n < 81) ? cls_b[n] : box_b[n - 81];
  for (int s = 0; s < nsplit; ++s)
    v += P[(size_t)s * (1024 * 512) + (size_t)m * 512 + n];
  out[idx] = v;
}

// ---------------------------------------------------------------------------
extern "C" void kernel_launch(void* const* d_in, const int* in_sizes, int n_in,
                              void* d_out, int out_size, void* d_ws, size_t ws_size,
                              hipStream_t stream) {
  const float* features = (const float*)d_in[0];
  const float* prop     = (const float*)d_in[1];
  const float* gt       = (const float*)d_in[2];
  const float* rnd      = (const float*)d_in[4];
  const float* fc1_w    = (const float*)d_in[5];
  const float* fc1_b    = (const float*)d_in[6];
  const float* fc2_w    = (const float*)d_in[7];
  const float* fc2_b    = (const float*)d_in[8];
  const float* cls_w    = (const float*)d_in[9];
  const float* cls_b    = (const float*)d_in[10];
  const float* box_w    = (const float*)d_in[11];
  const float* box_b    = (const float*)d_in[12];
  float* out = (float*)d_out;

  char* base = (char*)d_ws;
  // phase-1 layout
  float* fT   = (float*)(base + 0);                    //  8,388,608 B
  float* rois = (float*)(base + 8388608);              //     16,384 B
  char*  p2   = base + 8404992;                        // phase-2 region base
  f16* A1hi = (f16*)(base + 8404992);                  // 25,690,112 B
  f16* A1lo = (f16*)(base + 34095104);                 // 25,690,112 B
  f16* W1   = (f16*)(base + 59785216);                 // 25,690,112 B
  float* P1 = (float*)(base + 85475328);               // s1 * 4,194,304 B
  // FC1 split-K: 8 if ws allows (119 MB), else 4 (102 MB)
  int s1 = (ws_size >= (size_t)85475328 + 8ull * 4194304) ? 8 : 4;
  // phase-2 buffers overlay dead A1/W1 region (all used only after FC1)
  f16* A2hi = (f16*)(p2 + 0);          //  2,097,152
  f16* A2lo = (f16*)(p2 + 2097152);    //  2,097,152
  f16* W2   = (f16*)(p2 + 4194304);    //  2,097,152
  f16* A3hi = (f16*)(p2 + 6291456);    //  2,097,152
  f16* A3lo = (f16*)(p2 + 8388608);    //  2,097,152
  f16* W3   = (f16*)(p2 + 10485760);   //  1,048,576
  float* P2 = (float*)(p2 + 11534336); // 33,554,432 (8 splits)
  float* P3 = (float*)(p2 + 45088768); //  8,388,608 (4 splits)

  k_transpose<<<dim3(128, 8, B_), dim3(32, 8), 0, stream>>>(features, fT);
  k_select<<<dim3(B_), dim3(1024), 0, stream>>>(prop, gt, rnd, rois);
  k_roialign<<<dim3(49, 64), dim3(256), 0, stream>>>(fT, rois, A1hi, A1lo);
  k_convw<<<dim3(6272), dim3(256), 0, stream>>>(fc1_w, nullptr, W1, KT1, 1);
  // FC1: 1024 x 12544 x 1024
  k_gemm_mfma<<<dim3(8, 8, s1), dim3(256), 0, stream>>>(A1hi, A1lo, W1, P1,
                                                        1024, KT1, KT1 / s1);
  k_combine<<<dim3(512), dim3(256), 0, stream>>>(P1, fc1_b, A2hi, A2lo, s1);
  k_convw<<<dim3(512), dim3(256), 0, stream>>>(fc2_w, nullptr, W2, KT2, 0);
  // FC2: 1024 x 1024 x 1024
  k_gemm_mfma<<<dim3(8, 8, 8), dim3(256), 0, stream>>>(A2hi, A2lo, W2, P2,
                                                       1024, KT2, KT2 / 8);
  k_combine<<<dim3(512), dim3(256), 0, stream>>>(P2, fc2_b, A3hi, A3lo, 8);
  k_convw<<<dim3(256), dim3(256), 0, stream>>>(cls_w, box_w, W3, KT2, 2);
  // heads: 1024 x 1024 x 512(padded 401)
  k_gemm_mfma<<<dim3(8, 4, 4), dim3(256), 0, stream>>>(A3hi, A3lo, W3, P3,
                                                       512, KT2, KT2 / 4);
  k_out<<<dim3((RTOT * OUTC + 255) / 256), dim3(256), 0, stream>>>(
      P3, cls_b, box_b, out, 4);
}

// Round 3
// 416.152 us; speedup vs baseline: 4.3778x; 2.0791x over previous
//
#include <hip/hip_runtime.h>
#include <cstdint>
#include <cstddef>

// ---- problem constants ----
constexpr int B_   = 2;
constexpr int N_   = 2000;
constexpr int M_   = 64;
constexpr int NB_  = N_ + M_;       // 2064
constexpr int C_   = 256;
constexpr int H_   = 64;
constexpr int W_   = 64;
constexpr int RPI  = 512;
constexpr int RTOT = B_ * RPI;      // 1024
constexpr int FG_CAP_ = 128;
constexpr int D_   = C_ * 49;       // 12544
constexpr int FC_  = 1024;
constexpr int OUTC = 401;           // 81 + 320
constexpr int KT1  = D_ / 32;       // 392 k-tiles for FC1
constexpr int KT2  = FC_ / 32;      // 32 k-tiles for FC2/heads
constexpr float IOU_T = 0.5f;

typedef _Float16 f16;
typedef f16   f16x8 __attribute__((ext_vector_type(8)));
typedef float f32x4 __attribute__((ext_vector_type(4)));

__device__ __forceinline__ void tile_load16(const void* g, void* l) {
  __builtin_amdgcn_global_load_lds(
      (const __attribute__((address_space(1))) unsigned int*)g,
      (__attribute__((address_space(3))) unsigned int*)l, 16, 0, 0);
}

// ---------------------------------------------------------------------------
// K0: features (B,C,H,W) -> (B,H*W,C)
// ---------------------------------------------------------------------------
__global__ __launch_bounds__(256) void k_transpose(const float* __restrict__ in,
                                                   float* __restrict__ out) {
  __shared__ float tile[32][33];
  int b = blockIdx.z, hw0 = blockIdx.x * 32, c0 = blockIdx.y * 32;
  int tx = threadIdx.x, ty = threadIdx.y;
#pragma unroll
  for (int i = ty; i < 32; i += 8)
    tile[i][tx] = in[((size_t)b * C_ + c0 + i) * (H_ * W_) + hw0 + tx];
  __syncthreads();
#pragma unroll
  for (int i = ty; i < 32; i += 8)
    out[((size_t)b * (H_ * W_) + hw0 + i) * C_ + c0 + tx] = tile[tx][i];
}

// ---------------------------------------------------------------------------
// S1: IoU match -> fg flags + fg count. One block (1024 thr) per image.
// ---------------------------------------------------------------------------
__global__ __launch_bounds__(1024) void k_iou(const float* __restrict__ prop,
                                              const float* __restrict__ gt,
                                              unsigned char* __restrict__ fg,
                                              int* __restrict__ cnt) {
  __shared__ float s_gt[M_ * 4];
  __shared__ float s_area[M_];
  __shared__ int s_cnt;
  int b = blockIdx.x, t = threadIdx.x;
  if (t == 0) s_cnt = 0;
  if (t < M_ * 4) s_gt[t] = gt[(size_t)b * M_ * 4 + t];
  __syncthreads();
  if (t < M_) {
    float x1 = s_gt[t*4], y1 = s_gt[t*4+1], x2 = s_gt[t*4+2], y2 = s_gt[t*4+3];
    s_area[t] = (x2 - x1) * (y2 - y1);
  }
  __syncthreads();
  int local = 0;
  for (int j = t; j < NB_; j += 1024) {
    float bx1, by1, bx2, by2;
    if (j < N_) {
      const float* p = prop + ((size_t)b * N_ + j) * 4;
      bx1 = p[0]; by1 = p[1]; bx2 = p[2]; by2 = p[3];
    } else {
      const float* p = s_gt + (j - N_) * 4;
      bx1 = p[0]; by1 = p[1]; bx2 = p[2]; by2 = p[3];
    }
    float area_p = (bx2 - bx1) * (by2 - by1);
    float best = 0.f;
    for (int g = 0; g < M_; ++g) {
      float lx = fmaxf(s_gt[g*4], bx1),   lyv = fmaxf(s_gt[g*4+1], by1);
      float rx = fminf(s_gt[g*4+2], bx2), ry  = fminf(s_gt[g*4+3], by2);
      float w = fmaxf(rx - lx, 0.f), h = fmaxf(ry - lyv, 0.f);
      float inter = w * h;
      float iou = inter > 0.f ? inter / (s_area[g] + area_p - inter) : 0.f;
      best = fmaxf(best, iou);
    }
    int f = (best >= IOU_T) ? 1 : 0;
    fg[(size_t)b * NB_ + j] = (unsigned char)f;
    local += f;
  }
  atomicAdd(&s_cnt, local);
  __syncthreads();
  if (t == 0) cnt[b] = s_cnt;
}

// ---------------------------------------------------------------------------
// S2: stable rank among same class -> sel trit. One thread per candidate,
// k-loop over LDS copies. grid (5, B), block 512.
// ---------------------------------------------------------------------------
__global__ __launch_bounds__(512) void k_rank(const float* __restrict__ rnd,
                                              const unsigned char* __restrict__ fg,
                                              const int* __restrict__ cnt,
                                              unsigned char* __restrict__ sel) {
  __shared__ float s_rand[NB_];
  __shared__ unsigned char s_fg[NB_];
  int b = blockIdx.y, t = threadIdx.x;
  for (int j = t; j < NB_; j += 512) {
    s_rand[j] = rnd[(size_t)b * NB_ + j];
    s_fg[j]   = fg[(size_t)b * NB_ + j];
  }
  __syncthreads();
  int j = blockIdx.x * 512 + t;
  if (j >= NB_) return;
  int fgcnt  = cnt[b];
  int num_fg = min(fgcnt, FG_CAP_);
  int num_bg = min(RPI - num_fg, NB_ - fgcnt);
  int myfg = (int)s_fg[j];
  float rj = s_rand[j];
  int rank = 0;
  for (int k = 0; k < NB_; ++k) {
    if ((int)s_fg[k] == myfg) {
      float rk = s_rand[k];
      rank += (rk < rj || (rk == rj && k < j)) ? 1 : 0;
    }
  }
  int lim = myfg ? num_fg : num_bg;
  sel[(size_t)b * NB_ + j] =
      (rank < lim) ? (unsigned char)(myfg ? 2 : 1) : (unsigned char)0;
}

// ---------------------------------------------------------------------------
// S3: lax.top_k placement via ballot prefix scan. One wave per image.
// Output order: sel==2 ascending j, then sel==1 ascending, then filler.
// ---------------------------------------------------------------------------
__global__ __launch_bounds__(64) void k_place(const float* __restrict__ prop,
                                              const float* __restrict__ gt,
                                              const int* __restrict__ cnt,
                                              const unsigned char* __restrict__ sel,
                                              float* __restrict__ rois) {
  int b = blockIdx.x, L = threadIdx.x;
  int fgcnt  = cnt[b];
  int num_fg = min(fgcnt, FG_CAP_);
  int num_bg = min(RPI - num_fg, NB_ - fgcnt);
  int S = num_fg + num_bg;
  int t2 = 0, t1 = 0, t0 = 0;
  unsigned long long lt = (L == 0) ? 0ull : ((~0ull) >> (64 - L));
  for (int c = 0; c < (NB_ + 63) / 64; ++c) {
    int j = c * 64 + L;
    int s = (j < NB_) ? (int)sel[(size_t)b * NB_ + j] : -1;
    unsigned long long m2 = __ballot(s == 2);
    unsigned long long m1 = __ballot(s == 1);
    unsigned long long m0 = __ballot(s == 0);
    int pos = -1;
    if (s == 2) {
      pos = t2 + __popcll(m2 & lt);
    } else if (s == 1) {
      pos = num_fg + t1 + __popcll(m1 & lt);
    } else if (s == 0) {
      int p0 = t0 + __popcll(m0 & lt);
      if (S + p0 < RPI) pos = S + p0;
    }
    if (pos >= 0) {
      const float* p = (j < N_) ? (prop + ((size_t)b * N_ + j) * 4)
                                : (gt + ((size_t)b * M_ + (j - N_)) * 4);
      float* o = rois + ((size_t)b * RPI + pos) * 4;
      o[0] = p[0]; o[1] = p[1]; o[2] = p[2]; o[3] = p[3];
    }
    t2 += __popcll(m2); t1 += __popcll(m1); t0 += __popcll(m0);
  }
}

// ---------------------------------------------------------------------------
// K2: ROI align -> A1 hi/lo fp16 fragment-linear directly.
// ---------------------------------------------------------------------------
__global__ __launch_bounds__(256) void k_roialign(const float* __restrict__ fT,
                                                  const float* __restrict__ rois,
                                                  f16* __restrict__ Ahi,
                                                  f16* __restrict__ Alo) {
  __shared__ float sv[8][257];
  int bin = blockIdx.x, mt = blockIdx.y;
  int c = threadIdx.x;
  int by = bin / 7, bx = bin % 7;
  for (int pass = 0; pass < 2; ++pass) {
    for (int r8 = 0; r8 < 8; ++r8) {
      int r = mt * 16 + pass * 8 + r8;
      const float* rp = rois + (size_t)r * 4;
      float x1 = rp[0] * 0.0625f - 0.5f;
      float y1 = rp[1] * 0.0625f - 0.5f;
      float x2 = rp[2] * 0.0625f - 0.5f;
      float y2 = rp[3] * 0.0625f - 0.5f;
      float stx = (x2 - x1) * (1.0f / 7.0f);
      float sty = (y2 - y1) * (1.0f / 7.0f);
      const float* fb = fT + (size_t)(r >> 9) * H_ * W_ * C_;
      float acc = 0.f;
#pragma unroll
      for (int s = 0; s < 4; ++s) {
        int oy = s >> 1, ox = s & 1;
        float xs = x1 + ((float)(2 * bx + ox) + 0.5f) * 0.5f * stx;
        float ys = y1 + ((float)(2 * by + oy) + 0.5f) * 0.5f * sty;
        xs = fminf(fmaxf(xs, 0.f), (float)(W_ - 1));
        ys = fminf(fmaxf(ys, 0.f), (float)(H_ - 1));
        int x0 = (int)floorf(xs), y0 = (int)floorf(ys);
        int x1i = min(x0 + 1, W_ - 1), y1i = min(y0 + 1, H_ - 1);
        float lx = xs - (float)x0, ly = ys - (float)y0;
        float v00 = fb[((size_t)y0 * W_ + x0) * C_ + c];
        float v01 = fb[((size_t)y0 * W_ + x1i) * C_ + c];
        float v10 = fb[((size_t)y1i * W_ + x0) * C_ + c];
        float v11 = fb[((size_t)y1i * W_ + x1i) * C_ + c];
        acc += v00*(1.f-ly)*(1.f-lx) + v01*(1.f-ly)*lx + v10*ly*(1.f-lx) + v11*ly*lx;
      }
      sv[r8][c] = acc * 0.25f;
    }
    __syncthreads();
    int kt   = c >> 5;
    int l5   = c & 31;
    int quad = l5 >> 3;
    int r8   = l5 & 7;
    int lane = quad * 16 + pass * 8 + r8;
    int cbase = kt * 32 + quad * 8;
    f16x8 hv, lv;
#pragma unroll
    for (int jj = 0; jj < 8; ++jj) {
      float v = sv[r8][cbase + jj];
      f16 h = (f16)v;
      hv[jj] = h;
      lv[jj] = (f16)(v - (float)h);
    }
    size_t off = ((size_t)(mt * KT1 + bin * 8 + kt) * 64 + lane) * 8;
    *(f16x8*)(Ahi + off) = hv;
    *(f16x8*)(Alo + off) = lv;
    __syncthreads();
  }
}

// ---------------------------------------------------------------------------
// K3: weight -> fp16 fragment-linear. mode 0: direct (ldb=1024);
// mode 1: fc1 row-permute d=(k&255)*49+(k>>8); mode 2: concat cls|box pad-512.
// ---------------------------------------------------------------------------
__global__ __launch_bounds__(256) void k_convw(const float* __restrict__ src,
                                               const float* __restrict__ src2,
                                               f16* __restrict__ dst,
                                               int KTtot, int mode) {
  int q = blockIdx.x * 256 + threadIdx.x;
  int lane = q & 63, tile = q >> 6;
  int nt = tile / KTtot, kt = tile - nt * KTtot;
  int n  = nt * 16 + (lane & 15);
  int k0 = kt * 32 + (lane >> 4) * 8;
  f16x8 h;
#pragma unroll
  for (int jj = 0; jj < 8; ++jj) {
    int k = k0 + jj;
    float v;
    if (mode == 0) {
      v = src[(size_t)k * 1024 + n];
    } else if (mode == 1) {
      int row = (k & 255) * 49 + (k >> 8);
      v = src[(size_t)row * 1024 + n];
    } else {
      v = (n < 81) ? src[(size_t)k * 81 + n]
                   : ((n < 401) ? src2[(size_t)k * 320 + (n - 81)] : 0.f);
    }
    h[jj] = (f16)v;
  }
  *(f16x8*)(dst + (size_t)q * 8) = h;
}

// ---------------------------------------------------------------------------
// K4: MFMA GEMM. BM=BN=128, BK=32, 4 waves (2x2) each 64x64.
// ---------------------------------------------------------------------------
__global__ __launch_bounds__(256, 2) void k_gemm_mfma(
    const f16* __restrict__ Ahi, const f16* __restrict__ Alo,
    const f16* __restrict__ Bw, float* __restrict__ P,
    int N, int KTtot, int ktPerSplit) {
  __shared__ f16 sAh[8 * 512];
  __shared__ f16 sAl[8 * 512];
  __shared__ f16 sB[8 * 512];
  int tid = threadIdx.x;
  int lane = tid & 63, w = tid >> 6;
  int wm = w >> 1, wn = w & 1;
  int bm = blockIdx.x, bn = blockIdx.y, z = blockIdx.z;
  int kt0 = z * ktPerSplit, ktEnd = kt0 + ktPerSplit;

  f32x4 acc[4][4];
#pragma unroll
  for (int i = 0; i < 4; ++i)
#pragma unroll
    for (int j = 0; j < 4; ++j) {
      f32x4 zv = {0.f, 0.f, 0.f, 0.f};
      acc[i][j] = zv;
    }

  for (int kt = kt0; kt < ktEnd; ++kt) {
#pragma unroll
    for (int tt = 0; tt < 6; ++tt) {
      int t = 6 * w + tt;
      const f16* g;
      f16* l;
      if (t < 8)       { g = Ahi + ((size_t)(bm*8 + t)      * KTtot + kt) * 512; l = sAh + t * 512; }
      else if (t < 16) { g = Alo + ((size_t)(bm*8 + (t-8))  * KTtot + kt) * 512; l = sAl + (t-8) * 512; }
      else             { g = Bw  + ((size_t)(bn*8 + (t-16)) * KTtot + kt) * 512; l = sB  + (t-16) * 512; }
      tile_load16(g + lane * 8, l);
    }
    __syncthreads();
    f16x8 ah[4], al[4], bw[4];
#pragma unroll
    for (int i = 0; i < 4; ++i) {
      ah[i] = *(const f16x8*)(sAh + (wm*4 + i) * 512 + lane * 8);
      al[i] = *(const f16x8*)(sAl + (wm*4 + i) * 512 + lane * 8);
      bw[i] = *(const f16x8*)(sB  + (wn*4 + i) * 512 + lane * 8);
    }
#pragma unroll
    for (int i = 0; i < 4; ++i)
#pragma unroll
      for (int j = 0; j < 4; ++j) {
        acc[i][j] = __builtin_amdgcn_mfma_f32_16x16x32_f16(ah[i], bw[j], acc[i][j], 0, 0, 0);
        acc[i][j] = __builtin_amdgcn_mfma_f32_16x16x32_f16(al[i], bw[j], acc[i][j], 0, 0, 0);
      }
    __syncthreads();
  }

  int quad = lane >> 4, cl = lane & 15;
  float* Pz = P + (size_t)z * 1024 * (size_t)N;
#pragma unroll
  for (int i = 0; i < 4; ++i) {
    int row = bm * 128 + wm * 64 + i * 16 + quad * 4;
#pragma unroll
    for (int j = 0; j < 4; ++j) {
      int col = bn * 128 + wn * 64 + j * 16 + cl;
#pragma unroll
      for (int r = 0; r < 4; ++r)
        Pz[(size_t)(row + r) * N + col] = acc[i][j][r];
    }
  }
}

// ---------------------------------------------------------------------------
// K5: split-K reduce + bias + relu -> next layer's A hi/lo frag-linear
// ---------------------------------------------------------------------------
__global__ __launch_bounds__(256) void k_combine(const float* __restrict__ P,
                                                 const float* __restrict__ bias,
                                                 f16* __restrict__ Ahi,
                                                 f16* __restrict__ Alo,
                                                 int nsplit) {
  int q = blockIdx.x * 256 + threadIdx.x;
  int lane = q & 63, tile = q >> 6;
  int mt = tile >> 5, kt = tile & 31;
  int m  = mt * 16 + (lane & 15);
  int n0 = kt * 32 + (lane >> 4) * 8;
  float v[8];
#pragma unroll
  for (int jj = 0; jj < 8; ++jj) v[jj] = bias[n0 + jj];
  for (int s = 0; s < nsplit; ++s) {
    const float* p = P + (size_t)s * 1048576 + (size_t)m * 1024 + n0;
#pragma unroll
    for (int jj = 0; jj < 8; ++jj) v[jj] += p[jj];
  }
  f16x8 hv, lv;
#pragma unroll
  for (int jj = 0; jj < 8; ++jj) {
    float x = fmaxf(v[jj], 0.f);
    f16 h = (f16)x;
    hv[jj] = h;
    lv[jj] = (f16)(x - (float)h);
  }
  *(f16x8*)(Ahi + (size_t)q * 8) = hv;
  *(f16x8*)(Alo + (size_t)q * 8) = lv;
}

// ---------------------------------------------------------------------------
// K6: heads split-K reduce + concat bias -> out (1024 x 401 fp32)
// ---------------------------------------------------------------------------
__global__ __launch_bounds__(256) void k_out(const float* __restrict__ P,
                                             const float* __restrict__ cls_b,
                                             const float* __restrict__ box_b,
                                             float* __restrict__ out, int nsplit) {
  int idx = blockIdx.x * 256 + threadIdx.x;
  if (idx >= RTOT * OUTC) return;
  int m = idx / OUTC, n = idx - m * OUTC;
  float v = (n < 81) ? cls_b[n] : box_b[n - 81];
  for (int s = 0; s < nsplit; ++s)
    v += P[(size_t)s * (1024 * 512) + (size_t)m * 512 + n];
  out[idx] = v;
}

// ---------------------------------------------------------------------------
extern "C" void kernel_launch(void* const* d_in, const int* in_sizes, int n_in,
                              void* d_out, int out_size, void* d_ws, size_t ws_size,
                              hipStream_t stream) {
  const float* features = (const float*)d_in[0];
  const float* prop     = (const float*)d_in[1];
  const float* gt       = (const float*)d_in[2];
  const float* rnd      = (const float*)d_in[4];
  const float* fc1_w    = (const float*)d_in[5];
  const float* fc1_b    = (const float*)d_in[6];
  const float* fc2_w    = (const float*)d_in[7];
  const float* fc2_b    = (const float*)d_in[8];
  const float* cls_w    = (const float*)d_in[9];
  const float* cls_b    = (const float*)d_in[10];
  const float* box_w    = (const float*)d_in[11];
  const float* box_b    = (const float*)d_in[12];
  float* out = (float*)d_out;

  char* base = (char*)d_ws;
  float* fT   = (float*)(base + 0);                    //  8,388,608 B
  float* rois = (float*)(base + 8388608);              //     16,384 B
  char*  p2   = base + 8404992;
  f16* A1hi = (f16*)(base + 8404992);                  // 25,690,112 B
  f16* A1lo = (f16*)(base + 34095104);                 // 25,690,112 B
  f16* W1   = (f16*)(base + 59785216);                 // 25,690,112 B
  float* P1 = (float*)(base + 85475328);
  int s1 = (ws_size >= (size_t)85475328 + 8ull * 4194304) ? 8 : 4;
  // phase-2 overlays (used only after FC1)
  f16* A2hi = (f16*)(p2 + 0);
  f16* A2lo = (f16*)(p2 + 2097152);
  f16* W2   = (f16*)(p2 + 4194304);
  f16* A3hi = (f16*)(p2 + 6291456);
  f16* A3lo = (f16*)(p2 + 8388608);
  f16* W3   = (f16*)(p2 + 10485760);
  float* P2 = (float*)(p2 + 11534336);
  float* P3 = (float*)(p2 + 45088768);
  // selection scratch: overlays P1 region (read before FC1 GEMM writes it)
  unsigned char* g_fg  = (unsigned char*)(base + 85475328);
  unsigned char* g_sel = (unsigned char*)(base + 85475328 + 4160);
  int*           g_cnt = (int*)(base + 85475328 + 8320);

  k_transpose<<<dim3(128, 8, B_), dim3(32, 8), 0, stream>>>(features, fT);
  k_iou<<<dim3(B_), dim3(1024), 0, stream>>>(prop, gt, g_fg, g_cnt);
  k_rank<<<dim3((NB_ + 511) / 512, B_), dim3(512), 0, stream>>>(rnd, g_fg, g_cnt, g_sel);
  k_place<<<dim3(B_), dim3(64), 0, stream>>>(prop, gt, g_cnt, g_sel, rois);
  k_roialign<<<dim3(49, 64), dim3(256), 0, stream>>>(fT, rois, A1hi, A1lo);
  k_convw<<<dim3(6272), dim3(256), 0, stream>>>(fc1_w, nullptr, W1, KT1, 1);
  k_gemm_mfma<<<dim3(8, 8, s1), dim3(256), 0, stream>>>(A1hi, A1lo, W1, P1,
                                                        1024, KT1, KT1 / s1);
  k_combine<<<dim3(512), dim3(256), 0, stream>>>(P1, fc1_b, A2hi, A2lo, s1);
  k_convw<<<dim3(512), dim3(256), 0, stream>>>(fc2_w, nullptr, W2, KT2, 0);
  k_gemm_mfma<<<dim3(8, 8, 8), dim3(256), 0, stream>>>(A2hi, A2lo, W2, P2,
                                                       1024, KT2, KT2 / 8);
  k_combine<<<dim3(512), dim3(256), 0, stream>>>(P2, fc2_b, A3hi, A3lo, 8);
  k_convw<<<dim3(256), dim3(256), 0, stream>>>(cls_w, box_w, W3, KT2, 2);
  k_gemm_mfma<<<dim3(8, 4, 4), dim3(256), 0, stream>>>(A3hi, A3lo, W3, P3,
                                                       512, KT2, KT2 / 4);
  k_out<<<dim3((RTOT * OUTC + 255) / 256), dim3(256), 0, stream>>>(
      P3, cls_b, box_b, out, 4);
}

// Round 4
// 359.369 us; speedup vs baseline: 5.0695x; 1.1580x over previous
//
#include <hip/hip_runtime.h>
#include <cstdint>
#include <cstddef>

// ---- problem constants ----
constexpr int B_   = 2;
constexpr int N_   = 2000;
constexpr int M_   = 64;
constexpr int NB_  = N_ + M_;       // 2064
constexpr int C_   = 256;
constexpr int H_   = 64;
constexpr int W_   = 64;
constexpr int RPI  = 512;
constexpr int RTOT = B_ * RPI;      // 1024
constexpr int FG_CAP_ = 128;
constexpr int D_   = C_ * 49;       // 12544
constexpr int FC_  = 1024;
constexpr int OUTC = 401;           // 81 + 320
constexpr int KT1  = D_ / 32;       // 392 k-tiles for FC1
constexpr int KT2  = FC_ / 32;      // 32 k-tiles for FC2/heads
constexpr float IOU_T = 0.5f;

typedef _Float16 f16;
typedef f16   f16x8 __attribute__((ext_vector_type(8)));
typedef float f32x4 __attribute__((ext_vector_type(4)));

__device__ __forceinline__ void tile_load16(const void* g, void* l) {
  __builtin_amdgcn_global_load_lds(
      (const __attribute__((address_space(1))) unsigned int*)g,
      (__attribute__((address_space(3))) unsigned int*)l, 16, 0, 0);
}

// ---------------------------------------------------------------------------
// K0: features (B,C,H,W) -> (B,H*W,C)
// ---------------------------------------------------------------------------
__global__ __launch_bounds__(256) void k_transpose(const float* __restrict__ in,
                                                   float* __restrict__ out) {
  __shared__ float tile[32][33];
  int b = blockIdx.z, hw0 = blockIdx.x * 32, c0 = blockIdx.y * 32;
  int tx = threadIdx.x, ty = threadIdx.y;
#pragma unroll
  for (int i = ty; i < 32; i += 8)
    tile[i][tx] = in[((size_t)b * C_ + c0 + i) * (H_ * W_) + hw0 + tx];
  __syncthreads();
#pragma unroll
  for (int i = ty; i < 32; i += 8)
    out[((size_t)b * (H_ * W_) + hw0 + i) * C_ + c0 + tx] = tile[tx][i];
}

// ---------------------------------------------------------------------------
// S1: IoU match -> fg flags + fg count. One block (1024 thr) per image.
// ---------------------------------------------------------------------------
__global__ __launch_bounds__(1024) void k_iou(const float* __restrict__ prop,
                                              const float* __restrict__ gt,
                                              unsigned char* __restrict__ fg,
                                              int* __restrict__ cnt) {
  __shared__ float s_gt[M_ * 4];
  __shared__ float s_area[M_];
  __shared__ int s_cnt;
  int b = blockIdx.x, t = threadIdx.x;
  if (t == 0) s_cnt = 0;
  if (t < M_ * 4) s_gt[t] = gt[(size_t)b * M_ * 4 + t];
  __syncthreads();
  if (t < M_) {
    float x1 = s_gt[t*4], y1 = s_gt[t*4+1], x2 = s_gt[t*4+2], y2 = s_gt[t*4+3];
    s_area[t] = (x2 - x1) * (y2 - y1);
  }
  __syncthreads();
  int local = 0;
  for (int j = t; j < NB_; j += 1024) {
    float bx1, by1, bx2, by2;
    if (j < N_) {
      const float* p = prop + ((size_t)b * N_ + j) * 4;
      bx1 = p[0]; by1 = p[1]; bx2 = p[2]; by2 = p[3];
    } else {
      const float* p = s_gt + (j - N_) * 4;
      bx1 = p[0]; by1 = p[1]; bx2 = p[2]; by2 = p[3];
    }
    float area_p = (bx2 - bx1) * (by2 - by1);
    float best = 0.f;
    for (int g = 0; g < M_; ++g) {
      float lx = fmaxf(s_gt[g*4], bx1),   lyv = fmaxf(s_gt[g*4+1], by1);
      float rx = fminf(s_gt[g*4+2], bx2), ry  = fminf(s_gt[g*4+3], by2);
      float w = fmaxf(rx - lx, 0.f), h = fmaxf(ry - lyv, 0.f);
      float inter = w * h;
      float iou = inter > 0.f ? inter / (s_area[g] + area_p - inter) : 0.f;
      best = fmaxf(best, iou);
    }
    int f = (best >= IOU_T) ? 1 : 0;
    fg[(size_t)b * NB_ + j] = (unsigned char)f;
    local += f;
  }
  atomicAdd(&s_cnt, local);
  __syncthreads();
  if (t == 0) cnt[b] = s_cnt;
}

// ---------------------------------------------------------------------------
// S2: branchless rank via combined u64 key. Per-class rank = global rank
// minus class offset (fg keys [2,3) > all bg keys [0,1)). Key packs
// (float_bits(2*fg+rand) << 11) | j -> lexicographic u64 compare implements
// JAX's stable tie-break exactly. k-loop is wave-uniform -> broadcast b128.
// ---------------------------------------------------------------------------
__global__ __launch_bounds__(256) void k_rank(const float* __restrict__ rnd,
                                              const unsigned char* __restrict__ fg,
                                              const int* __restrict__ cnt,
                                              unsigned char* __restrict__ sel) {
  __shared__ unsigned long long s_key[NB_];  // 16.5 KB
  int b = blockIdx.y, t = threadIdx.x;
  for (int j = t; j < NB_; j += 256) {
    float r = rnd[(size_t)b * NB_ + j];
    int f = (int)fg[(size_t)b * NB_ + j];
    float ck = r + 2.0f * (float)f;
    unsigned int ib = __float_as_uint(ck);
    s_key[j] = ((unsigned long long)ib << 11) | (unsigned int)j;
  }
  __syncthreads();
  int j = blockIdx.x * 256 + t;
  int jj = (j < NB_) ? j : 0;
  unsigned long long uj = s_key[jj];
  int rank_all = 0;
  const uint4* kp = (const uint4*)s_key;  // 2 keys per uint4, NB_ even
#pragma unroll 4
  for (int k2 = 0; k2 < NB_ / 2; ++k2) {
    uint4 v = kp[k2];
    unsigned long long k0 = ((unsigned long long)v.y << 32) | v.x;
    unsigned long long k1 = ((unsigned long long)v.w << 32) | v.z;
    rank_all += (k0 < uj) ? 1 : 0;
    rank_all += (k1 < uj) ? 1 : 0;
  }
  if (j >= NB_) return;
  int fgcnt  = cnt[b];
  int num_fg = min(fgcnt, FG_CAP_);
  int num_bg = min(RPI - num_fg, NB_ - fgcnt);
  int myfg   = (uj >> 11) >= 0x40000000ull ? 1 : 0;  // key >= 2.0f
  int rank   = rank_all - (myfg ? (NB_ - fgcnt) : 0);
  int lim    = myfg ? num_fg : num_bg;
  sel[(size_t)b * NB_ + j] =
      (rank < lim) ? (unsigned char)(myfg ? 2 : 1) : (unsigned char)0;
}

// ---------------------------------------------------------------------------
// S3: lax.top_k placement via ballot prefix scan. One wave per image.
// ---------------------------------------------------------------------------
__global__ __launch_bounds__(64) void k_place(const float* __restrict__ prop,
                                              const float* __restrict__ gt,
                                              const int* __restrict__ cnt,
                                              const unsigned char* __restrict__ sel,
                                              float* __restrict__ rois) {
  int b = blockIdx.x, L = threadIdx.x;
  int fgcnt  = cnt[b];
  int num_fg = min(fgcnt, FG_CAP_);
  int num_bg = min(RPI - num_fg, NB_ - fgcnt);
  int S = num_fg + num_bg;
  int t2 = 0, t1 = 0, t0 = 0;
  unsigned long long lt = (L == 0) ? 0ull : ((~0ull) >> (64 - L));
  for (int c = 0; c < (NB_ + 63) / 64; ++c) {
    int j = c * 64 + L;
    int s = (j < NB_) ? (int)sel[(size_t)b * NB_ + j] : -1;
    unsigned long long m2 = __ballot(s == 2);
    unsigned long long m1 = __ballot(s == 1);
    unsigned long long m0 = __ballot(s == 0);
    int pos = -1;
    if (s == 2) {
      pos = t2 + __popcll(m2 & lt);
    } else if (s == 1) {
      pos = num_fg + t1 + __popcll(m1 & lt);
    } else if (s == 0) {
      int p0 = t0 + __popcll(m0 & lt);
      if (S + p0 < RPI) pos = S + p0;
    }
    if (pos >= 0) {
      const float* p = (j < N_) ? (prop + ((size_t)b * N_ + j) * 4)
                                : (gt + ((size_t)b * M_ + (j - N_)) * 4);
      float* o = rois + ((size_t)b * RPI + pos) * 4;
      o[0] = p[0]; o[1] = p[1]; o[2] = p[2]; o[3] = p[3];
    }
    t2 += __popcll(m2); t1 += __popcll(m1); t0 += __popcll(m0);
  }
}

// ---------------------------------------------------------------------------
// K2: ROI align -> A1 hi/lo fp16 fragment-linear directly.
// ---------------------------------------------------------------------------
__global__ __launch_bounds__(256) void k_roialign(const float* __restrict__ fT,
                                                  const float* __restrict__ rois,
                                                  f16* __restrict__ Ahi,
                                                  f16* __restrict__ Alo) {
  __shared__ float sv[8][257];
  int bin = blockIdx.x, mt = blockIdx.y;
  int c = threadIdx.x;
  int by = bin / 7, bx = bin % 7;
  for (int pass = 0; pass < 2; ++pass) {
    for (int r8 = 0; r8 < 8; ++r8) {
      int r = mt * 16 + pass * 8 + r8;
      const float* rp = rois + (size_t)r * 4;
      float x1 = rp[0] * 0.0625f - 0.5f;
      float y1 = rp[1] * 0.0625f - 0.5f;
      float x2 = rp[2] * 0.0625f - 0.5f;
      float y2 = rp[3] * 0.0625f - 0.5f;
      float stx = (x2 - x1) * (1.0f / 7.0f);
      float sty = (y2 - y1) * (1.0f / 7.0f);
      const float* fb = fT + (size_t)(r >> 9) * H_ * W_ * C_;
      float acc = 0.f;
#pragma unroll
      for (int s = 0; s < 4; ++s) {
        int oy = s >> 1, ox = s & 1;
        float xs = x1 + ((float)(2 * bx + ox) + 0.5f) * 0.5f * stx;
        float ys = y1 + ((float)(2 * by + oy) + 0.5f) * 0.5f * sty;
        xs = fminf(fmaxf(xs, 0.f), (float)(W_ - 1));
        ys = fminf(fmaxf(ys, 0.f), (float)(H_ - 1));
        int x0 = (int)floorf(xs), y0 = (int)floorf(ys);
        int x1i = min(x0 + 1, W_ - 1), y1i = min(y0 + 1, H_ - 1);
        float lx = xs - (float)x0, ly = ys - (float)y0;
        float v00 = fb[((size_t)y0 * W_ + x0) * C_ + c];
        float v01 = fb[((size_t)y0 * W_ + x1i) * C_ + c];
        float v10 = fb[((size_t)y1i * W_ + x0) * C_ + c];
        float v11 = fb[((size_t)y1i * W_ + x1i) * C_ + c];
        acc += v00*(1.f-ly)*(1.f-lx) + v01*(1.f-ly)*lx + v10*ly*(1.f-lx) + v11*ly*lx;
      }
      sv[r8][c] = acc * 0.25f;
    }
    __syncthreads();
    int kt   = c >> 5;
    int l5   = c & 31;
    int quad = l5 >> 3;
    int r8   = l5 & 7;
    int lane = quad * 16 + pass * 8 + r8;
    int cbase = kt * 32 + quad * 8;
    f16x8 hv, lv;
#pragma unroll
    for (int jj = 0; jj < 8; ++jj) {
      float v = sv[r8][cbase + jj];
      f16 h = (f16)v;
      hv[jj] = h;
      lv[jj] = (f16)(v - (float)h);
    }
    size_t off = ((size_t)(mt * KT1 + bin * 8 + kt) * 64 + lane) * 8;
    *(f16x8*)(Ahi + off) = hv;
    *(f16x8*)(Alo + off) = lv;
    __syncthreads();
  }
}

// ---------------------------------------------------------------------------
// K3: weight -> fp16 fragment-linear. mode 0: direct (ldb=1024);
// mode 1: fc1 row-permute d=(k&255)*49+(k>>8); mode 2: concat cls|box pad-512.
// ---------------------------------------------------------------------------
__global__ __launch_bounds__(256) void k_convw(const float* __restrict__ src,
                                               const float* __restrict__ src2,
                                               f16* __restrict__ dst,
                                               int KTtot, int mode) {
  int q = blockIdx.x * 256 + threadIdx.x;
  int lane = q & 63, tile = q >> 6;
  int nt = tile / KTtot, kt = tile - nt * KTtot;
  int n  = nt * 16 + (lane & 15);
  int k0 = kt * 32 + (lane >> 4) * 8;
  f16x8 h;
#pragma unroll
  for (int jj = 0; jj < 8; ++jj) {
    int k = k0 + jj;
    float v;
    if (mode == 0) {
      v = src[(size_t)k * 1024 + n];
    } else if (mode == 1) {
      int row = (k & 255) * 49 + (k >> 8);
      v = src[(size_t)row * 1024 + n];
    } else {
      v = (n < 81) ? src[(size_t)k * 81 + n]
                   : ((n < 401) ? src2[(size_t)k * 320 + (n - 81)] : 0.f);
    }
    h[jj] = (f16)v;
  }
  *(f16x8*)(dst + (size_t)q * 8) = h;
}

// ---------------------------------------------------------------------------
// K4: MFMA GEMM. BM=BN=128, BK=32, 4 waves (2x2) each 64x64.
// ---------------------------------------------------------------------------
__global__ __launch_bounds__(256, 2) void k_gemm_mfma(
    const f16* __restrict__ Ahi, const f16* __restrict__ Alo,
    const f16* __restrict__ Bw, float* __restrict__ P,
    int N, int KTtot, int ktPerSplit) {
  __shared__ f16 sAh[8 * 512];
  __shared__ f16 sAl[8 * 512];
  __shared__ f16 sB[8 * 512];
  int tid = threadIdx.x;
  int lane = tid & 63, w = tid >> 6;
  int wm = w >> 1, wn = w & 1;
  int bm = blockIdx.x, bn = blockIdx.y, z = blockIdx.z;
  int kt0 = z * ktPerSplit, ktEnd = kt0 + ktPerSplit;

  f32x4 acc[4][4];
#pragma unroll
  for (int i = 0; i < 4; ++i)
#pragma unroll
    for (int j = 0; j < 4; ++j) {
      f32x4 zv = {0.f, 0.f, 0.f, 0.f};
      acc[i][j] = zv;
    }

  for (int kt = kt0; kt < ktEnd; ++kt) {
#pragma unroll
    for (int tt = 0; tt < 6; ++tt) {
      int t = 6 * w + tt;
      const f16* g;
      f16* l;
      if (t < 8)       { g = Ahi + ((size_t)(bm*8 + t)      * KTtot + kt) * 512; l = sAh + t * 512; }
      else if (t < 16) { g = Alo + ((size_t)(bm*8 + (t-8))  * KTtot + kt) * 512; l = sAl + (t-8) * 512; }
      else             { g = Bw  + ((size_t)(bn*8 + (t-16)) * KTtot + kt) * 512; l = sB  + (t-16) * 512; }
      tile_load16(g + lane * 8, l);
    }
    __syncthreads();
    f16x8 ah[4], al[4], bw[4];
#pragma unroll
    for (int i = 0; i < 4; ++i) {
      ah[i] = *(const f16x8*)(sAh + (wm*4 + i) * 512 + lane * 8);
      al[i] = *(const f16x8*)(sAl + (wm*4 + i) * 512 + lane * 8);
      bw[i] = *(const f16x8*)(sB  + (wn*4 + i) * 512 + lane * 8);
    }
#pragma unroll
    for (int i = 0; i < 4; ++i)
#pragma unroll
      for (int j = 0; j < 4; ++j) {
        acc[i][j] = __builtin_amdgcn_mfma_f32_16x16x32_f16(ah[i], bw[j], acc[i][j], 0, 0, 0);
        acc[i][j] = __builtin_amdgcn_mfma_f32_16x16x32_f16(al[i], bw[j], acc[i][j], 0, 0, 0);
      }
    __syncthreads();
  }

  int quad = lane >> 4, cl = lane & 15;
  float* Pz = P + (size_t)z * 1024 * (size_t)N;
#pragma unroll
  for (int i = 0; i < 4; ++i) {
    int row = bm * 128 + wm * 64 + i * 16 + quad * 4;
#pragma unroll
    for (int j = 0; j < 4; ++j) {
      int col = bn * 128 + wn * 64 + j * 16 + cl;
#pragma unroll
      for (int r = 0; r < 4; ++r)
        Pz[(size_t)(row + r) * N + col] = acc[i][j][r];
    }
  }
}

// ---------------------------------------------------------------------------
// K5: split-K reduce + bias + relu -> next layer's A hi/lo frag-linear
// ---------------------------------------------------------------------------
__global__ __launch_bounds__(256) void k_combine(const float* __restrict__ P,
                                                 const float* __restrict__ bias,
                                                 f16* __restrict__ Ahi,
                                                 f16* __restrict__ Alo,
                                                 int nsplit) {
  int q = blockIdx.x * 256 + threadIdx.x;
  int lane = q & 63, tile = q >> 6;
  int mt = tile >> 5, kt = tile & 31;
  int m  = mt * 16 + (lane & 15);
  int n0 = kt * 32 + (lane >> 4) * 8;
  float v[8];
#pragma unroll
  for (int jj = 0; jj < 8; ++jj) v[jj] = bias[n0 + jj];
  for (int s = 0; s < nsplit; ++s) {
    const float* p = P + (size_t)s * 1048576 + (size_t)m * 1024 + n0;
#pragma unroll
    for (int jj = 0; jj < 8; ++jj) v[jj] += p[jj];
  }
  f16x8 hv, lv;
#pragma unroll
  for (int jj = 0; jj < 8; ++jj) {
    float x = fmaxf(v[jj], 0.f);
    f16 h = (f16)x;
    hv[jj] = h;
    lv[jj] = (f16)(x - (float)h);
  }
  *(f16x8*)(Ahi + (size_t)q * 8) = hv;
  *(f16x8*)(Alo + (size_t)q * 8) = lv;
}

// ---------------------------------------------------------------------------
// K6: heads split-K reduce + concat bias -> out (1024 x 401 fp32)
// ---------------------------------------------------------------------------
__global__ __launch_bounds__(256) void k_out(const float* __restrict__ P,
                                             const float* __restrict__ cls_b,
                                             const float* __restrict__ box_b,
                                             float* __restrict__ out, int nsplit) {
  int idx = blockIdx.x * 256 + threadIdx.x;
  if (idx >= RTOT * OUTC) return;
  int m = idx / OUTC, n = idx - m * OUTC;
  float v = (n < 81) ? cls_b[n] : box_b[n - 81];
  for (int s = 0; s < nsplit; ++s)
    v += P[(size_t)s * (1024 * 512) + (size_t)m * 512 + n];
  out[idx] = v;
}

// ---------------------------------------------------------------------------
extern "C" void kernel_launch(void* const* d_in, const int* in_sizes, int n_in,
                              void* d_out, int out_size, void* d_ws, size_t ws_size,
                              hipStream_t stream) {
  const float* features = (const float*)d_in[0];
  const float* prop     = (const float*)d_in[1];
  const float* gt       = (const float*)d_in[2];
  const float* rnd      = (const float*)d_in[4];
  const float* fc1_w    = (const float*)d_in[5];
  const float* fc1_b    = (const float*)d_in[6];
  const float* fc2_w    = (const float*)d_in[7];
  const float* fc2_b    = (const float*)d_in[8];
  const float* cls_w    = (const float*)d_in[9];
  const float* cls_b    = (const float*)d_in[10];
  const float* box_w    = (const float*)d_in[11];
  const float* box_b    = (const float*)d_in[12];
  float* out = (float*)d_out;

  char* base = (char*)d_ws;
  float* fT   = (float*)(base + 0);                    //  8,388,608 B
  float* rois = (float*)(base + 8388608);              //     16,384 B
  char*  p2   = base + 8404992;
  f16* A1hi = (f16*)(base + 8404992);                  // 25,690,112 B
  f16* A1lo = (f16*)(base + 34095104);                 // 25,690,112 B
  f16* W1   = (f16*)(base + 59785216);                 // 25,690,112 B
  float* P1 = (float*)(base + 85475328);
  int s1 = (ws_size >= (size_t)85475328 + 8ull * 4194304) ? 8 : 4;
  // phase-2 overlays (used only after FC1)
  f16* A2hi = (f16*)(p2 + 0);
  f16* A2lo = (f16*)(p2 + 2097152);
  f16* W2   = (f16*)(p2 + 4194304);
  f16* A3hi = (f16*)(p2 + 6291456);
  f16* A3lo = (f16*)(p2 + 8388608);
  f16* W3   = (f16*)(p2 + 10485760);
  float* P2 = (float*)(p2 + 11534336);
  float* P3 = (float*)(p2 + 45088768);
  // selection scratch: overlays P1 region (read before FC1 GEMM writes it)
  unsigned char* g_fg  = (unsigned char*)(base + 85475328);
  unsigned char* g_sel = (unsigned char*)(base + 85475328 + 4160);
  int*           g_cnt = (int*)(base + 85475328 + 8320);

  k_transpose<<<dim3(128, 8, B_), dim3(32, 8), 0, stream>>>(features, fT);
  k_iou<<<dim3(B_), dim3(1024), 0, stream>>>(prop, gt, g_fg, g_cnt);
  k_rank<<<dim3((NB_ + 255) / 256, B_), dim3(256), 0, stream>>>(rnd, g_fg, g_cnt, g_sel);
  k_place<<<dim3(B_), dim3(64), 0, stream>>>(prop, gt, g_cnt, g_sel, rois);
  k_roialign<<<dim3(49, 64), dim3(256), 0, stream>>>(fT, rois, A1hi, A1lo);
  k_convw<<<dim3(6272), dim3(256), 0, stream>>>(fc1_w, nullptr, W1, KT1, 1);
  k_gemm_mfma<<<dim3(8, 8, s1), dim3(256), 0, stream>>>(A1hi, A1lo, W1, P1,
                                                        1024, KT1, KT1 / s1);
  k_combine<<<dim3(512), dim3(256), 0, stream>>>(P1, fc1_b, A2hi, A2lo, s1);
  k_convw<<<dim3(512), dim3(256), 0, stream>>>(fc2_w, nullptr, W2, KT2, 0);
  k_gemm_mfma<<<dim3(8, 8, 8), dim3(256), 0, stream>>>(A2hi, A2lo, W2, P2,
                                                       1024, KT2, KT2 / 8);
  k_combine<<<dim3(512), dim3(256), 0, stream>>>(P2, fc2_b, A3hi, A3lo, 8);
  k_convw<<<dim3(256), dim3(256), 0, stream>>>(cls_w, box_w, W3, KT2, 2);
  k_gemm_mfma<<<dim3(8, 4, 4), dim3(256), 0, stream>>>(A3hi, A3lo, W3, P3,
                                                       512, KT2, KT2 / 4);
  k_out<<<dim3((RTOT * OUTC + 255) / 256), dim3(256), 0, stream>>>(
      P3, cls_b, box_b, out, 4);
}

// Round 5
// 351.595 us; speedup vs baseline: 5.1816x; 1.0221x over previous
//
#include <hip/hip_runtime.h>
#include <cstdint>
#include <cstddef>

// ---- problem constants ----
constexpr int B_   = 2;
constexpr int N_   = 2000;
constexpr int M_   = 64;
constexpr int NB_  = N_ + M_;       // 2064
constexpr int C_   = 256;
constexpr int H_   = 64;
constexpr int W_   = 64;
constexpr int RPI  = 512;
constexpr int RTOT = B_ * RPI;      // 1024
constexpr int FG_CAP_ = 128;
constexpr int D_   = C_ * 49;       // 12544
constexpr int FC_  = 1024;
constexpr int OUTC = 401;           // 81 + 320
constexpr int KT1  = D_ / 32;       // 392 k-tiles for FC1
constexpr int KT2  = FC_ / 32;      // 32 k-tiles for FC2/heads
constexpr float IOU_T = 0.5f;

typedef _Float16 f16;
typedef f16   f16x8 __attribute__((ext_vector_type(8)));
typedef float f32x4 __attribute__((ext_vector_type(4)));

__device__ __forceinline__ void tile_load16(const void* g, void* l) {
  __builtin_amdgcn_global_load_lds(
      (const __attribute__((address_space(1))) unsigned int*)g,
      (__attribute__((address_space(3))) unsigned int*)l, 16, 0, 0);
}

// ---------------------------------------------------------------------------
// K0: features (B,C,H,W) -> (B,H*W,C)
// ---------------------------------------------------------------------------
__global__ __launch_bounds__(256) void k_transpose(const float* __restrict__ in,
                                                   float* __restrict__ out) {
  __shared__ float tile[32][33];
  int b = blockIdx.z, hw0 = blockIdx.x * 32, c0 = blockIdx.y * 32;
  int tx = threadIdx.x, ty = threadIdx.y;
#pragma unroll
  for (int i = ty; i < 32; i += 8)
    tile[i][tx] = in[((size_t)b * C_ + c0 + i) * (H_ * W_) + hw0 + tx];
  __syncthreads();
#pragma unroll
  for (int i = ty; i < 32; i += 8)
    out[((size_t)b * (H_ * W_) + hw0 + i) * C_ + c0 + tx] = tile[tx][i];
}

// ---------------------------------------------------------------------------
// S1: IoU match -> fg flags + fg count. One block (1024 thr) per image.
// ---------------------------------------------------------------------------
__global__ __launch_bounds__(1024) void k_iou(const float* __restrict__ prop,
                                              const float* __restrict__ gt,
                                              unsigned char* __restrict__ fg,
                                              int* __restrict__ cnt) {
  __shared__ float s_gt[M_ * 4];
  __shared__ float s_area[M_];
  __shared__ int s_cnt;
  int b = blockIdx.x, t = threadIdx.x;
  if (t == 0) s_cnt = 0;
  if (t < M_ * 4) s_gt[t] = gt[(size_t)b * M_ * 4 + t];
  __syncthreads();
  if (t < M_) {
    float x1 = s_gt[t*4], y1 = s_gt[t*4+1], x2 = s_gt[t*4+2], y2 = s_gt[t*4+3];
    s_area[t] = (x2 - x1) * (y2 - y1);
  }
  __syncthreads();
  int local = 0;
  for (int j = t; j < NB_; j += 1024) {
    float bx1, by1, bx2, by2;
    if (j < N_) {
      const float* p = prop + ((size_t)b * N_ + j) * 4;
      bx1 = p[0]; by1 = p[1]; bx2 = p[2]; by2 = p[3];
    } else {
      const float* p = s_gt + (j - N_) * 4;
      bx1 = p[0]; by1 = p[1]; bx2 = p[2]; by2 = p[3];
    }
    float area_p = (bx2 - bx1) * (by2 - by1);
    float best = 0.f;
    for (int g = 0; g < M_; ++g) {
      float lx = fmaxf(s_gt[g*4], bx1),   lyv = fmaxf(s_gt[g*4+1], by1);
      float rx = fminf(s_gt[g*4+2], bx2), ry  = fminf(s_gt[g*4+3], by2);
      float w = fmaxf(rx - lx, 0.f), h = fmaxf(ry - lyv, 0.f);
      float inter = w * h;
      float iou = inter > 0.f ? inter / (s_area[g] + area_p - inter) : 0.f;
      best = fmaxf(best, iou);
    }
    int f = (best >= IOU_T) ? 1 : 0;
    fg[(size_t)b * NB_ + j] = (unsigned char)f;
    local += f;
  }
  atomicAdd(&s_cnt, local);
  __syncthreads();
  if (t == 0) cnt[b] = s_cnt;
}

// ---------------------------------------------------------------------------
// S2: branchless rank via combined u64 key (exact JAX stable tie-break).
// ---------------------------------------------------------------------------
__global__ __launch_bounds__(256) void k_rank(const float* __restrict__ rnd,
                                              const unsigned char* __restrict__ fg,
                                              const int* __restrict__ cnt,
                                              unsigned char* __restrict__ sel) {
  __shared__ unsigned long long s_key[NB_];
  int b = blockIdx.y, t = threadIdx.x;
  for (int j = t; j < NB_; j += 256) {
    float r = rnd[(size_t)b * NB_ + j];
    int f = (int)fg[(size_t)b * NB_ + j];
    float ck = r + 2.0f * (float)f;
    unsigned int ib = __float_as_uint(ck);
    s_key[j] = ((unsigned long long)ib << 11) | (unsigned int)j;
  }
  __syncthreads();
  int j = blockIdx.x * 256 + t;
  int jj = (j < NB_) ? j : 0;
  unsigned long long uj = s_key[jj];
  int rank_all = 0;
  const uint4* kp = (const uint4*)s_key;
#pragma unroll 4
  for (int k2 = 0; k2 < NB_ / 2; ++k2) {
    uint4 v = kp[k2];
    unsigned long long k0 = ((unsigned long long)v.y << 32) | v.x;
    unsigned long long k1 = ((unsigned long long)v.w << 32) | v.z;
    rank_all += (k0 < uj) ? 1 : 0;
    rank_all += (k1 < uj) ? 1 : 0;
  }
  if (j >= NB_) return;
  int fgcnt  = cnt[b];
  int num_fg = min(fgcnt, FG_CAP_);
  int num_bg = min(RPI - num_fg, NB_ - fgcnt);
  int myfg   = (uj >> 11) >= 0x40000000ull ? 1 : 0;
  int rank   = rank_all - (myfg ? (NB_ - fgcnt) : 0);
  int lim    = myfg ? num_fg : num_bg;
  sel[(size_t)b * NB_ + j] =
      (rank < lim) ? (unsigned char)(myfg ? 2 : 1) : (unsigned char)0;
}

// ---------------------------------------------------------------------------
// S3: lax.top_k placement via ballot prefix scan. One wave per image.
// ---------------------------------------------------------------------------
__global__ __launch_bounds__(64) void k_place(const float* __restrict__ prop,
                                              const float* __restrict__ gt,
                                              const int* __restrict__ cnt,
                                              const unsigned char* __restrict__ sel,
                                              float* __restrict__ rois) {
  int b = blockIdx.x, L = threadIdx.x;
  int fgcnt  = cnt[b];
  int num_fg = min(fgcnt, FG_CAP_);
  int num_bg = min(RPI - num_fg, NB_ - fgcnt);
  int S = num_fg + num_bg;
  int t2 = 0, t1 = 0, t0 = 0;
  unsigned long long lt = (L == 0) ? 0ull : ((~0ull) >> (64 - L));
  for (int c = 0; c < (NB_ + 63) / 64; ++c) {
    int j = c * 64 + L;
    int s = (j < NB_) ? (int)sel[(size_t)b * NB_ + j] : -1;
    unsigned long long m2 = __ballot(s == 2);
    unsigned long long m1 = __ballot(s == 1);
    unsigned long long m0 = __ballot(s == 0);
    int pos = -1;
    if (s == 2) {
      pos = t2 + __popcll(m2 & lt);
    } else if (s == 1) {
      pos = num_fg + t1 + __popcll(m1 & lt);
    } else if (s == 0) {
      int p0 = t0 + __popcll(m0 & lt);
      if (S + p0 < RPI) pos = S + p0;
    }
    if (pos >= 0) {
      const float* p = (j < N_) ? (prop + ((size_t)b * N_ + j) * 4)
                                : (gt + ((size_t)b * M_ + (j - N_)) * 4);
      float* o = rois + ((size_t)b * RPI + pos) * 4;
      o[0] = p[0]; o[1] = p[1]; o[2] = p[2]; o[3] = p[3];
    }
    t2 += __popcll(m2); t1 += __popcll(m1); t0 += __popcll(m0);
  }
}

// ---------------------------------------------------------------------------
// K2: ROI align -> A1 fp16 fragment-linear (hi only).
// ---------------------------------------------------------------------------
__global__ __launch_bounds__(256) void k_roialign(const float* __restrict__ fT,
                                                  const float* __restrict__ rois,
                                                  f16* __restrict__ Ahi) {
  __shared__ float sv[8][257];
  int bin = blockIdx.x, mt = blockIdx.y;
  int c = threadIdx.x;
  int by = bin / 7, bx = bin % 7;
  for (int pass = 0; pass < 2; ++pass) {
    for (int r8 = 0; r8 < 8; ++r8) {
      int r = mt * 16 + pass * 8 + r8;
      const float* rp = rois + (size_t)r * 4;
      float x1 = rp[0] * 0.0625f - 0.5f;
      float y1 = rp[1] * 0.0625f - 0.5f;
      float x2 = rp[2] * 0.0625f - 0.5f;
      float y2 = rp[3] * 0.0625f - 0.5f;
      float stx = (x2 - x1) * (1.0f / 7.0f);
      float sty = (y2 - y1) * (1.0f / 7.0f);
      const float* fb = fT + (size_t)(r >> 9) * H_ * W_ * C_;
      float acc = 0.f;
#pragma unroll
      for (int s = 0; s < 4; ++s) {
        int oy = s >> 1, ox = s & 1;
        float xs = x1 + ((float)(2 * bx + ox) + 0.5f) * 0.5f * stx;
        float ys = y1 + ((float)(2 * by + oy) + 0.5f) * 0.5f * sty;
        xs = fminf(fmaxf(xs, 0.f), (float)(W_ - 1));
        ys = fminf(fmaxf(ys, 0.f), (float)(H_ - 1));
        int x0 = (int)floorf(xs), y0 = (int)floorf(ys);
        int x1i = min(x0 + 1, W_ - 1), y1i = min(y0 + 1, H_ - 1);
        float lx = xs - (float)x0, ly = ys - (float)y0;
        float v00 = fb[((size_t)y0 * W_ + x0) * C_ + c];
        float v01 = fb[((size_t)y0 * W_ + x1i) * C_ + c];
        float v10 = fb[((size_t)y1i * W_ + x0) * C_ + c];
        float v11 = fb[((size_t)y1i * W_ + x1i) * C_ + c];
        acc += v00*(1.f-ly)*(1.f-lx) + v01*(1.f-ly)*lx + v10*ly*(1.f-lx) + v11*ly*lx;
      }
      sv[r8][c] = acc * 0.25f;
    }
    __syncthreads();
    int kt   = c >> 5;
    int l5   = c & 31;
    int quad = l5 >> 3;
    int r8   = l5 & 7;
    int lane = quad * 16 + pass * 8 + r8;
    int cbase = kt * 32 + quad * 8;
    f16x8 hv;
#pragma unroll
    for (int jj = 0; jj < 8; ++jj) hv[jj] = (f16)sv[r8][cbase + jj];
    size_t off = ((size_t)(mt * KT1 + bin * 8 + kt) * 64 + lane) * 8;
    *(f16x8*)(Ahi + off) = hv;
    __syncthreads();
  }
}

// ---------------------------------------------------------------------------
// K3: weight -> fp16 fragment-linear via LDS-staged transpose (coalesced
// reads AND writes). mode 0: direct ld=1024; mode 1: fc1 row-permute
// row=(k&255)*49+(k>>8); mode 2: concat cls(81)|box(320) pad to 512.
// grid (KTtot, Ntiles/4), block 256. LDS tile padded [32][65] (no 4-way alias).
// ---------------------------------------------------------------------------
__global__ __launch_bounds__(256) void k_convw(const float* __restrict__ src,
                                               const float* __restrict__ src2,
                                               f16* __restrict__ dst,
                                               int KTtot, int mode) {
  __shared__ float tile[32][65];
  int kt = blockIdx.x, ng = blockIdx.y;
  int t = threadIdx.x;
  int n0 = ng * 64;
  // load: 32 k-rows x 64 n, coalesced 256B per row segment
  int col = t & 63;
#pragma unroll
  for (int p = 0; p < 8; ++p) {
    int r = p * 4 + (t >> 6);
    int k = kt * 32 + r;
    float v;
    if (mode == 0) {
      v = src[(size_t)k * 1024 + n0 + col];
    } else if (mode == 1) {
      int row = (k & 255) * 49 + (k >> 8);
      v = src[(size_t)row * 1024 + n0 + col];
    } else {
      int n = n0 + col;
      v = (n < 81) ? src[(size_t)k * 81 + n]
                   : ((n < 401) ? src2[(size_t)k * 320 + (n - 81)] : 0.f);
    }
    tile[r][col] = v;
  }
  __syncthreads();
  // write: 4 frag tiles, 16B per thread
  int sub = t >> 6, lane = t & 63;
  int nt = ng * 4 + sub;
  int nl = lane & 15, kg = lane >> 4;
  f16x8 h;
#pragma unroll
  for (int e = 0; e < 8; ++e)
    h[e] = (f16)tile[kg * 8 + e][sub * 16 + nl];
  *(f16x8*)(dst + ((size_t)(nt * KTtot + kt) * 64 + lane) * 8) = h;
}

// ---------------------------------------------------------------------------
// K4: MFMA GEMM. BM=BN=128, BK=32, 4 waves (2x2) each 64x64, fp16 single-A.
// Per kt: 16 KB staged / 64 MFMA = m97 ratio.
// ---------------------------------------------------------------------------
__global__ __launch_bounds__(256, 2) void k_gemm_mfma(
    const f16* __restrict__ Ahi, const f16* __restrict__ Bw,
    float* __restrict__ P, int N, int KTtot, int ktPerSplit) {
  __shared__ f16 sAh[8 * 512];
  __shared__ f16 sB[8 * 512];
  int tid = threadIdx.x;
  int lane = tid & 63, w = tid >> 6;
  int wm = w >> 1, wn = w & 1;
  int bm = blockIdx.x, bn = blockIdx.y, z = blockIdx.z;
  int kt0 = z * ktPerSplit, ktEnd = kt0 + ktPerSplit;

  f32x4 acc[4][4];
#pragma unroll
  for (int i = 0; i < 4; ++i)
#pragma unroll
    for (int j = 0; j < 4; ++j) {
      f32x4 zv = {0.f, 0.f, 0.f, 0.f};
      acc[i][j] = zv;
    }

  for (int kt = kt0; kt < ktEnd; ++kt) {
#pragma unroll
    for (int tt = 0; tt < 4; ++tt) {
      int t = 4 * w + tt;
      const f16* g;
      f16* l;
      if (t < 8) { g = Ahi + ((size_t)(bm*8 + t)     * KTtot + kt) * 512; l = sAh + t * 512; }
      else       { g = Bw  + ((size_t)(bn*8 + (t-8)) * KTtot + kt) * 512; l = sB + (t-8) * 512; }
      tile_load16(g + lane * 8, l);
    }
    __syncthreads();
    f16x8 ah[4], bw[4];
#pragma unroll
    for (int i = 0; i < 4; ++i) {
      ah[i] = *(const f16x8*)(sAh + (wm*4 + i) * 512 + lane * 8);
      bw[i] = *(const f16x8*)(sB  + (wn*4 + i) * 512 + lane * 8);
    }
#pragma unroll
    for (int i = 0; i < 4; ++i)
#pragma unroll
      for (int j = 0; j < 4; ++j)
        acc[i][j] = __builtin_amdgcn_mfma_f32_16x16x32_f16(ah[i], bw[j], acc[i][j], 0, 0, 0);
    __syncthreads();
  }

  int quad = lane >> 4, cl = lane & 15;
  float* Pz = P + (size_t)z * 1024 * (size_t)N;
#pragma unroll
  for (int i = 0; i < 4; ++i) {
    int row = bm * 128 + wm * 64 + i * 16 + quad * 4;
#pragma unroll
    for (int j = 0; j < 4; ++j) {
      int col = bn * 128 + wn * 64 + j * 16 + cl;
#pragma unroll
      for (int r = 0; r < 4; ++r)
        Pz[(size_t)(row + r) * N + col] = acc[i][j][r];
    }
  }
}

// ---------------------------------------------------------------------------
// K5: split-K reduce + bias + relu -> next layer's A fp16 frag-linear
// ---------------------------------------------------------------------------
__global__ __launch_bounds__(256) void k_combine(const float* __restrict__ P,
                                                 const float* __restrict__ bias,
                                                 f16* __restrict__ Ahi,
                                                 int nsplit) {
  int q = blockIdx.x * 256 + threadIdx.x;
  int lane = q & 63, tile = q >> 6;
  int mt = tile >> 5, kt = tile & 31;
  int m  = mt * 16 + (lane & 15);
  int n0 = kt * 32 + (lane >> 4) * 8;
  float v[8];
#pragma unroll
  for (int jj = 0; jj < 8; ++jj) v[jj] = bias[n0 + jj];
  for (int s = 0; s < nsplit; ++s) {
    const float* p = P + (size_t)s * 1048576 + (size_t)m * 1024 + n0;
#pragma unroll
    for (int jj = 0; jj < 8; ++jj) v[jj] += p[jj];
  }
  f16x8 hv;
#pragma unroll
  for (int jj = 0; jj < 8; ++jj) hv[jj] = (f16)fmaxf(v[jj], 0.f);
  *(f16x8*)(Ahi + (size_t)q * 8) = hv;
}

// ---------------------------------------------------------------------------
// K6: heads split-K reduce + concat bias -> out (1024 x 401 fp32)
// ---------------------------------------------------------------------------
__global__ __launch_bounds__(256) void k_out(const float* __restrict__ P,
                                             const float* __restrict__ cls_b,
                                             const float* __restrict__ box_b,
                                             float* __restrict__ out, int nsplit) {
  int idx = blockIdx.x * 256 + threadIdx.x;
  if (idx >= RTOT * OUTC) return;
  int m = idx / OUTC, n = idx - m * OUTC;
  float v = (n < 81) ? cls_b[n] : box_b[n - 81];
  for (int s = 0; s < nsplit; ++s)
    v += P[(size_t)s * (1024 * 512) + (size_t)m * 512 + n];
  out[idx] = v;
}

// ---------------------------------------------------------------------------
extern "C" void kernel_launch(void* const* d_in, const int* in_sizes, int n_in,
                              void* d_out, int out_size, void* d_ws, size_t ws_size,
                              hipStream_t stream) {
  const float* features = (const float*)d_in[0];
  const float* prop     = (const float*)d_in[1];
  const float* gt       = (const float*)d_in[2];
  const float* rnd      = (const float*)d_in[4];
  const float* fc1_w    = (const float*)d_in[5];
  const float* fc1_b    = (const float*)d_in[6];
  const float* fc2_w    = (const float*)d_in[7];
  const float* fc2_b    = (const float*)d_in[8];
  const float* cls_w    = (const float*)d_in[9];
  const float* cls_b    = (const float*)d_in[10];
  const float* box_w    = (const float*)d_in[11];
  const float* box_b    = (const float*)d_in[12];
  float* out = (float*)d_out;

  char* base = (char*)d_ws;
  float* fT   = (float*)(base + 0);                    //  8,388,608 B
  float* rois = (float*)(base + 8388608);              //     16,384 B
  char*  p2   = base + 8404992;
  f16* A1hi = (f16*)(base + 8404992);                  // 25,690,112 B
  f16* W1   = (f16*)(base + 34095104);                 // 25,690,112 B
  float* P1 = (float*)(base + 59785216);               // s1 * 4,194,304 B
  int s1 = (ws_size >= (size_t)59785216 + 8ull * 4194304) ? 8 : 4;
  // phase-2 overlays (used only after FC1 GEMM) — reuse A1hi region
  f16* A2hi = (f16*)(p2 + 0);          // 2,097,152
  f16* W2   = (f16*)(p2 + 2097152);    // 2,097,152
  f16* A3hi = (f16*)(p2 + 4194304);    // 2,097,152
  f16* W3   = (f16*)(p2 + 6291456);    // 1,048,576
  float* P2 = (float*)(p2 + 7340032);  // 16,777,216 (4 splits)
  float* P3 = (float*)(p2 + 24117248); //  8,388,608 (4 splits)
  // selection scratch: overlays P1 region (read before FC1 GEMM writes it)
  unsigned char* g_fg  = (unsigned char*)(base + 59785216);
  unsigned char* g_sel = (unsigned char*)(base + 59785216 + 4160);
  int*           g_cnt = (int*)(base + 59785216 + 8320);

  k_transpose<<<dim3(128, 8, B_), dim3(32, 8), 0, stream>>>(features, fT);
  k_iou<<<dim3(B_), dim3(1024), 0, stream>>>(prop, gt, g_fg, g_cnt);
  k_rank<<<dim3((NB_ + 255) / 256, B_), dim3(256), 0, stream>>>(rnd, g_fg, g_cnt, g_sel);
  k_place<<<dim3(B_), dim3(64), 0, stream>>>(prop, gt, g_cnt, g_sel, rois);
  k_roialign<<<dim3(49, 64), dim3(256), 0, stream>>>(fT, rois, A1hi);
  k_convw<<<dim3(KT1, 16), dim3(256), 0, stream>>>(fc1_w, nullptr, W1, KT1, 1);
  // FC1: 1024 x 12544 x 1024
  k_gemm_mfma<<<dim3(8, 8, s1), dim3(256), 0, stream>>>(A1hi, W1, P1,
                                                        1024, KT1, KT1 / s1);
  k_combine<<<dim3(512), dim3(256), 0, stream>>>(P1, fc1_b, A2hi, s1);
  k_convw<<<dim3(KT2, 16), dim3(256), 0, stream>>>(fc2_w, nullptr, W2, KT2, 0);
  // FC2: 1024 x 1024 x 1024, split-K 4
  k_gemm_mfma<<<dim3(8, 8, 4), dim3(256), 0, stream>>>(A2hi, W2, P2,
                                                       1024, KT2, KT2 / 4);
  k_combine<<<dim3(512), dim3(256), 0, stream>>>(P2, fc2_b, A3hi, 4);
  k_convw<<<dim3(KT2, 8), dim3(256), 0, stream>>>(cls_w, box_w, W3, KT2, 2);
  // heads: 1024 x 1024 x 512(padded 401), split-K 4
  k_gemm_mfma<<<dim3(8, 4, 4), dim3(256), 0, stream>>>(A3hi, W3, P3,
                                                       512, KT2, KT2 / 4);
  k_out<<<dim3((RTOT * OUTC + 255) / 256), dim3(256), 0, stream>>>(
      P3, cls_b, box_b, out, 4);
}